// Round 7
// baseline (2754.529 us; speedup 1.0000x reference)
//
#include <hip/hip_runtime.h>

// Decoder, B=16, T=64, S=128, D_ENC=512, U=256, V=32000.
// Round 7: per-batch-pair GANG recurrence. 8 independent gangs (gang=blk&7,
// likely XCD-local) x 32 blocks, 2 batches per gang, private 32-block barrier.
// No cross-gang sync at all. Phase A: gates+attention (replicated per role
// block, each owns a 32-dim x slice). Phase B: z GEMV, j-slice per block,
// k-split intra-block via LDS.
// Epilogue: one bf16 MFMA vocab GEMM + exp + rowsum, deferred softmax scale.

#define NB 16
#define NT 64
#define NS 128
#define DE 512
#define NU 256
#define NV 32000
#define GBLK 32   // blocks per gang

// ws layout (floats); total 18.32 MB (<= proven available)
static const size_t OFF_KEYS = 0;         // keysT bf16 [16][256][128] = 262144 fl
static const size_t OFF_XT   = 262144;    // x [16][1024] fp32 (ctx|emb|h)
static const size_t OFF_BAR  = 278528;    // 8 gang counters, 64-int padded
static const size_t OFF_ZP   = 286720;    // zfull [16][1024]
static const size_t OFF_RS   = 352256;    // rowsums [1024]
static const size_t OFF_HBUF = 353296;    // Hb fragment-tiled bf16 = 131072 fl
static const size_t OFF_WDT  = 484368;    // wdT fragment-tiled bf16 = 4096000 fl

typedef __attribute__((ext_vector_type(8))) short bf16x8;
typedef __attribute__((ext_vector_type(4))) float f32x4;

__device__ __forceinline__ float bf2f(unsigned int us) { return __uint_as_float(us << 16); }
__device__ __forceinline__ unsigned short f2bf(float f) {
    unsigned int u = __float_as_uint(f);
    return (unsigned short)((u + 0x7fffu + ((u >> 16) & 1u)) >> 16);
}
__device__ __forceinline__ float rcp_fast(float x) { return __builtin_amdgcn_rcpf(x); }
__device__ __forceinline__ float sigm(float x) { return rcp_fast(1.0f + __expf(-x)); }
__device__ __forceinline__ float tanh1(float x) {
    float e = __expf(2.0f * x);
    return 1.0f - 2.0f * rcp_fast(e + 1.0f);
}

// coherent (L3-point) accesses for cross-block data: bypass non-coherent L2
__device__ __forceinline__ void cstore(float* p, float v) {
    __hip_atomic_store(p, v, __ATOMIC_RELAXED, __HIP_MEMORY_SCOPE_AGENT);
}
__device__ __forceinline__ float cload(const float* p) {
    return __hip_atomic_load(p, __ATOMIC_RELAXED, __HIP_MEMORY_SCOPE_AGENT);
}

// per-gang barrier: single monotonic counter, 32 arrivals per epoch.
// Fence-free: explicit vmcnt drain before arrival puts coherent stores at L3;
// pollers use relaxed loads only.
__device__ __forceinline__ void gangbar(int* cnt, int need) {
    __syncthreads();
    if (threadIdx.x == 0) {
        asm volatile("s_waitcnt vmcnt(0) lgkmcnt(0)" ::: "memory");
        __hip_atomic_fetch_add(cnt, 1, __ATOMIC_RELAXED, __HIP_MEMORY_SCOPE_AGENT);
        while (__hip_atomic_load(cnt, __ATOMIC_RELAXED, __HIP_MEMORY_SCOPE_AGENT) < need) {
            __builtin_amdgcn_s_sleep(1);
        }
        asm volatile("" ::: "memory");
    }
    __syncthreads();
}

// ---------------- init: rs, gang counters ----------------
__launch_bounds__(256)
__global__ void init_kernel(float* __restrict__ rs, int* __restrict__ bar) {
    int b = blockIdx.x, u = threadIdx.x;
    if (u < 64) rs[b * 64 + u] = 0.f;
    int idx = b * 256 + u;
    if (idx < 512) bar[idx] = 0;
}

// ---------------- keys^T = (enc @ W2 + b2)^T  -> keysT[b][u][s] bf16 ----------------
__launch_bounds__(256)
__global__ void keys_kernel(const float* __restrict__ enc, const float* __restrict__ W2,
                            const float* __restrict__ b2, unsigned short* __restrict__ keysT) {
    __shared__ float els[8 * DE];  // 16 KB
    int b = blockIdx.x >> 4, so = blockIdx.x & 15;
    int u = threadIdx.x;
    const float4* src = (const float4*)(enc + ((size_t)b * NS + so * 8) * DE);
    float4* dst = (float4*)els;
    for (int i = u; i < 8 * DE / 4; i += 256) dst[i] = src[i];
    __syncthreads();
    float bias = b2[u];
    float acc[8];
#pragma unroll
    for (int ss = 0; ss < 8; ss++) acc[ss] = bias;
#pragma unroll 4
    for (int d = 0; d < DE; d++) {
        float w = W2[d * NU + u];
#pragma unroll
        for (int ss = 0; ss < 8; ss++) acc[ss] = fmaf(els[ss * DE + d], w, acc[ss]);
    }
    unsigned int w0 = (unsigned int)f2bf(acc[0]) | ((unsigned int)f2bf(acc[1]) << 16);
    unsigned int w1 = (unsigned int)f2bf(acc[2]) | ((unsigned int)f2bf(acc[3]) << 16);
    unsigned int w2 = (unsigned int)f2bf(acc[4]) | ((unsigned int)f2bf(acc[5]) << 16);
    unsigned int w3 = (unsigned int)f2bf(acc[6]) | ((unsigned int)f2bf(acc[7]) << 16);
    *(uint4*)(keysT + ((size_t)b * NU + u) * NS + so * 8) = make_uint4(w0, w1, w2, w3);
}

// ---------------- Wd -> fragment-tiled bf16 ----------------
__launch_bounds__(256)
__global__ void wdtile_kernel(const float* __restrict__ Wd, unsigned short* __restrict__ wdT) {
    int id = blockIdx.x * 256 + threadIdx.x;  // 0 .. 1,023,999
    int l = id & 63, c16 = (id >> 6) & 7, ks = (id >> 9) & 7, p = id >> 12;
    int v = p * 128 + c16 * 16 + (l & 15);
    int k0 = ks * 32 + (l >> 4) * 8;
    unsigned int wout[4];
#pragma unroll
    for (int jj = 0; jj < 4; jj++) {
        unsigned int lo = f2bf(Wd[(size_t)(k0 + 2 * jj) * NV + v]);
        unsigned int hi = f2bf(Wd[(size_t)(k0 + 2 * jj + 1) * NV + v]);
        wout[jj] = lo | (hi << 16);
    }
    *(uint4*)(wdT + (size_t)id * 8) = make_uint4(wout[0], wout[1], wout[2], wout[3]);
}

// ---------------- persistent gang recurrence ----------------
__launch_bounds__(256, 1)
__global__ void recur_kernel(const int* __restrict__ dec, const float* __restrict__ enc,
                             const float* __restrict__ emb, const float* __restrict__ W1,
                             const float* __restrict__ b1, const float* __restrict__ Va,
                             const float* __restrict__ bV, const float* __restrict__ Wx,
                             const float* __restrict__ Wh, const float* __restrict__ b_lstm,
                             const float* __restrict__ h0, const float* __restrict__ c0,
                             const unsigned short* __restrict__ keysT, float* __restrict__ x,
                             float* __restrict__ zfull, unsigned short* __restrict__ Hb,
                             int* __restrict__ bar) {
    __shared__ float smem[2560];  // A: hl|qv|scp|red|attn|rctx ; B: xs[2][1024]|zpart[512]
    int tid = threadIdx.x;
    int gang = blockIdx.x & 7;    // likely XCD id (round-robin dispatch heuristic)
    int r = blockIdx.x >> 3;      // 0..31 within gang
    int bloc = r & 1;
    int role = r >> 1;            // 0..15
    int b = gang * 2 + bloc;
    int* cnt = bar + gang * 64;
    int nbar = 0;

    float* hl = smem;
    float* qv = smem + 256;
    float* scp = smem + 512;
    float* red = smem + 768;
    float* attn = smem + 896;
    float* rctx = smem + 1024;
    float* xs = smem;             // phase B
    float* zpart = smem + 2048;   // phase B: [8][2][32]

    int u = tid;
    float c_reg = c0[b * NU + u];
    const float* zb = zfull + b * 1024;
    float* xb = x + b * 1024;

    for (int it = 0; it <= NT; ++it) {
        // ---------- phase A: gates (it>0) + attention (it<NT); all blocks ----------
        {
            float hn;
            if (it > 0) {
                float zi = cload(zb + u) + b_lstm[u];
                float zf = cload(zb + 256 + u) + b_lstm[256 + u];
                float zg = cload(zb + 512 + u) + b_lstm[512 + u];
                float zo = cload(zb + 768 + u) + b_lstm[768 + u];
                float cn = sigm(zf) * c_reg + sigm(zi) * tanh1(zg);
                c_reg = cn;
                hn = sigm(zo) * tanh1(cn);
                if (role == 0) {  // one block per b writes Hb (fragment-tiled)
                    int rr = (it - 1) * NB + b;
                    int mp = rr >> 7, lr = rr & 127;
                    int chunk = ((u >> 5) * 8 + (lr >> 4)) * 64 + ((u >> 3) & 3) * 16 + (lr & 15);
                    Hb[(size_t)mp * 32768 + chunk * 8 + (u & 7)] = f2bf(hn);
                }
            } else {
                hn = h0[b * NU + u];
            }
            hl[u] = hn;
            __syncthreads();
            if (it < NT) {
                // q = h @ W1 + b1 (replicated per block)
                float a = b1[u];
#pragma unroll 4
                for (int d = 0; d < NU; d++) a = fmaf(hl[d], W1[d * NU + u], a);
                qv[u] = a;
                __syncthreads();
                // scores (replicated): thread = (s, u-half)
                int s = tid & 127, uh = tid >> 7;
                const unsigned short* kp = keysT + ((size_t)b * NU + uh * 128) * NS + s;
                float sc = 0.f;
#pragma unroll 4
                for (int uu = 0; uu < 128; uu++)
                    sc = fmaf(tanh1(qv[uh * 128 + uu] + bf2f(kp[(size_t)uu * NS])),
                              Va[uh * 128 + uu], sc);
                scp[uh * NS + s] = sc;
                __syncthreads();
                float scfull = 0.f, p = 0.f;
                if (tid < NS) {
                    scfull = scp[tid] + scp[NS + tid] + bV[0];
                    red[tid] = scfull;
                }
                __syncthreads();
                for (int off = 64; off >= 1; off >>= 1) {
                    if (tid < off) red[tid] = fmaxf(red[tid], red[tid + off]);
                    __syncthreads();
                }
                float m = red[0];
                __syncthreads();
                if (tid < NS) {
                    p = __expf(scfull - m);
                    red[tid] = p;
                }
                __syncthreads();
                for (int off = 64; off >= 1; off >>= 1) {
                    if (tid < off) red[tid] += red[tid + off];
                    __syncthreads();
                }
                float tot = red[0];
                if (tid < NS) attn[tid] = p / tot;
                __syncthreads();
                // ctx slice: this block owns d = role*32 .. +32
                int dl = tid & 31, sg = tid >> 5;  // 8 s-groups of 16
                const float* ep = enc + ((size_t)b * NS + sg * 16) * DE + role * 32 + dl;
                float cp = 0.f;
#pragma unroll
                for (int i2 = 0; i2 < 16; i2++)
                    cp = fmaf(attn[sg * 16 + i2], ep[(size_t)i2 * DE], cp);
                rctx[sg * 32 + dl] = cp;
                __syncthreads();
                if (tid < 32) {
                    float cv = 0.f;
#pragma unroll
                    for (int k = 0; k < 8; k++) cv += rctx[k * 32 + tid];
                    cstore(&xb[role * 32 + tid], cv);
                    if (role < 8) {  // emb slice
                        int tok = dec[b * NT + it];
                        tok = (tok < 0) ? 0 : (tok >= NV ? NV - 1 : tok);
                        cstore(&xb[512 + role * 32 + tid], emb[(size_t)tok * NU + role * 32 + tid]);
                    } else {  // h slice
                        cstore(&xb[768 + (role - 8) * 32 + tid], hl[(role - 8) * 32 + tid]);
                    }
                }
            }
        }
        if (it == NT) break;
        gangbar(cnt, (++nbar) * GBLK);

        // ---------- phase B: z[b][j] for gang's 2 batches; j-slice 32 per block ----------
        {
            const float* x0 = x + (size_t)(gang * 2) * 1024;
            const float* x1 = x + (size_t)(gang * 2 + 1) * 1024;
            for (int i = tid; i < 1024; i += 256) {
                xs[i] = cload(x0 + i);
                xs[1024 + i] = cload(x1 + i);
            }
            __syncthreads();
            int jl = tid & 31, kg = tid >> 5;  // j-lane, k-group (8 x 128)
            int j = r * 32 + jl;
            int kbase = kg * 128;
            const float* wp = (kbase < 768) ? (Wx + (size_t)kbase * 1024 + j)
                                            : (Wh + (size_t)(kbase - 768) * 1024 + j);
            float a0 = 0.f, a1 = 0.f, a2 = 0.f, a3 = 0.f;
#pragma unroll 4
            for (int kk = 0; kk < 128; kk += 2) {
                float w0 = wp[(size_t)kk * 1024];
                float w1 = wp[(size_t)(kk + 1) * 1024];
                a0 = fmaf(w0, xs[kbase + kk], a0);
                a1 = fmaf(w0, xs[1024 + kbase + kk], a1);
                a2 = fmaf(w1, xs[kbase + kk + 1], a2);
                a3 = fmaf(w1, xs[1024 + kbase + kk + 1], a3);
            }
            zpart[kg * 64 + jl] = a0 + a2;
            zpart[kg * 64 + 32 + jl] = a1 + a3;
            __syncthreads();
            if (tid < 64) {
                int jj = tid & 31, bl = tid >> 5;
                float sz = 0.f;
#pragma unroll
                for (int k = 0; k < 8; k++) sz += zpart[k * 64 + bl * 32 + jj];
                cstore(&zfull[(size_t)(gang * 2 + bl) * 1024 + r * 32 + jj], sz);
            }
        }
        gangbar(cnt, (++nbar) * GBLK);
    }
}

// ---------------- batched vocab GEMM + exp + rowsum ----------------
__launch_bounds__(256)
__global__ void gemm_kernel(const unsigned short* __restrict__ Hb,
                            const unsigned short* __restrict__ wdT,
                            const float* __restrict__ bd, float* __restrict__ out,
                            float* __restrict__ rs) {
    int w = (blockIdx.x & 7) * 250 + (blockIdx.x >> 3);
    int np = w >> 3, mp = w & 7;
    int wave = threadIdx.x >> 6, l = threadIdx.x & 63;
    int wm = wave >> 1, wn = wave & 1;
    const bf16x8* A = (const bf16x8*)Hb + (size_t)mp * 4096;
    const bf16x8* B = (const bf16x8*)wdT + (size_t)np * 4096;
    f32x4 acc[4][4];
#pragma unroll
    for (int mf = 0; mf < 4; mf++)
#pragma unroll
        for (int nf = 0; nf < 4; nf++) acc[mf][nf] = (f32x4){0.f, 0.f, 0.f, 0.f};
#pragma unroll
    for (int ks = 0; ks < 8; ks++) {
        bf16x8 av[4], bv[4];
#pragma unroll
        for (int mf = 0; mf < 4; mf++) av[mf] = A[(ks * 8 + wm * 4 + mf) * 64 + l];
#pragma unroll
        for (int nf = 0; nf < 4; nf++) bv[nf] = B[(ks * 8 + wn * 4 + nf) * 64 + l];
#pragma unroll
        for (int mf = 0; mf < 4; mf++)
#pragma unroll
            for (int nf = 0; nf < 4; nf++)
                acc[mf][nf] =
                    __builtin_amdgcn_mfma_f32_16x16x32_bf16(av[mf], bv[nf], acc[mf][nf], 0, 0, 0);
    }
    int colg = np * 128 + wn * 64;
    int rowg = mp * 128 + wm * 64;
#pragma unroll
    for (int mf = 0; mf < 4; mf++) {
        float rloc[4] = {0.f, 0.f, 0.f, 0.f};
#pragma unroll
        for (int nf = 0; nf < 4; nf++) {
            int col = colg + nf * 16 + (l & 15);
            float bdv = bd[col];
#pragma unroll
            for (int reg = 0; reg < 4; reg++) {
                int rr = rowg + mf * 16 + (l >> 4) * 4 + reg;  // rr = t*16 + b
                float p = __expf(acc[mf][nf][reg] + bdv);
                out[(size_t)((rr & 15) * NT + (rr >> 4)) * NV + col] = p;
                rloc[reg] += p;
            }
        }
#pragma unroll
        for (int reg = 0; reg < 4; reg++) {
            float v = rloc[reg];
            v += __shfl_xor(v, 1);
            v += __shfl_xor(v, 2);
            v += __shfl_xor(v, 4);
            v += __shfl_xor(v, 8);
            if ((l & 15) == 0) atomicAdd(&rs[rowg + mf * 16 + (l >> 4) * 4 + reg], v);
        }
    }
}

// ---------------- final softmax normalization ----------------
__launch_bounds__(256)
__global__ void scale_kernel(float* __restrict__ out, const float* __restrict__ rs) {
    int o = blockIdx.x;  // out row = b*64 + t
    int b = o >> 6, t = o & 63;
    float rinv = 1.0f / rs[t * NB + b];
    float4* op = (float4*)(out + (size_t)o * NV);
    for (int i = threadIdx.x; i < NV / 4; i += 256) {
        float4 v = op[i];
        v.x *= rinv; v.y *= rinv; v.z *= rinv; v.w *= rinv;
        op[i] = v;
    }
}

extern "C" void kernel_launch(void* const* d_in, const int* in_sizes, int n_in,
                              void* d_out, int out_size, void* d_ws, size_t ws_size,
                              hipStream_t stream) {
    const int* dec = (const int*)d_in[0];
    const float* enc = (const float*)d_in[1];
    const float* h0 = (const float*)d_in[2];
    const float* c0 = (const float*)d_in[3];
    const float* emb = (const float*)d_in[4];
    const float* W1 = (const float*)d_in[5];
    const float* b1 = (const float*)d_in[6];
    const float* W2 = (const float*)d_in[7];
    const float* b2 = (const float*)d_in[8];
    const float* Va = (const float*)d_in[9];
    const float* bV = (const float*)d_in[10];
    const float* Wx = (const float*)d_in[11];
    const float* Wh = (const float*)d_in[12];
    const float* b_lstm = (const float*)d_in[13];
    const float* Wd = (const float*)d_in[14];
    const float* bd = (const float*)d_in[15];
    float* out = (float*)d_out;
    float* ws = (float*)d_ws;

    unsigned short* keysT = (unsigned short*)(ws + OFF_KEYS);
    float* x = ws + OFF_XT;
    float* zfull = ws + OFF_ZP;
    float* ws_rs = ws + OFF_RS;
    int* bar = (int*)(ws + OFF_BAR);
    unsigned short* Hb = (unsigned short*)(ws + OFF_HBUF);
    unsigned short* wdT = (unsigned short*)(ws + OFF_WDT);

    init_kernel<<<16, 256, 0, stream>>>(ws_rs, bar);
    keys_kernel<<<256, 256, 0, stream>>>(enc, W2, b2, keysT);
    wdtile_kernel<<<4000, 256, 0, stream>>>(Wd, wdT);
    recur_kernel<<<256, 256, 0, stream>>>(dec, enc, emb, W1, b1, Va, bV, Wx, Wh, b_lstm,
                                          h0, c0, keysT, x, zfull, Hb, bar);
    gemm_kernel<<<2000, 256, 0, stream>>>(Hb, wdT, bd, out, ws_rs);
    scale_kernel<<<1024, 256, 0, stream>>>(out, ws_rs);
}

// Round 8
// 1456.444 us; speedup vs baseline: 1.8913x; 1.8913x over previous
//
#include <hip/hip_runtime.h>

// Decoder, B=16, T=64, S=128, D_ENC=512, U=256, V=32000.
// Round 8: cache-resident recurrence.
//   precompute: encWx[b][s][j] = enc[b]@Wx[:512]  (hoists ctx@Wx out of loop)
//               zemb[b][t][j]  = emb[tok]@Wx[512:768] + b_lstm (teacher forcing)
//   recurrence: 8 gangs x 32 blocks; each block = (batch, 64-j z-slice) with
//   its 96 weights/thread PINNED IN REGISTERS; gates+q+softmax replicated per
//   block; ONE gang barrier per step; only z (dbuf) crosses via L3 atomics.
// Epilogue: bf16 MFMA vocab GEMM + exp + rowsum, deferred softmax scale.

#define NB 16
#define NT 64
#define NS 128
#define DE 512
#define NU 256
#define NV 32000
#define GBLK 32

// ws layout (floats); encWx/zemb OVERLAP wdT region (recur before wdtile).
// total = 4,523,520 fl = 18.09 MB (<= 18.5 MB proven)
static const size_t OFF_KEYS  = 0;         // keysT bf16 [16][256][128]
static const size_t OFF_ZF    = 262144;    // zfull dbuf [2][16][1024]
static const size_t OFF_RS    = 294912;    // rowsums [1024]
static const size_t OFF_BAR   = 295936;    // 8 gang counters (512 ints padded)
static const size_t OFF_HBUF  = 296448;    // Hb fragment-tiled bf16 (131072 fl)
static const size_t OFF_ENCWX = 427520;    // [16][128][1024] fp32 (2,097,152)
static const size_t OFF_ZEMB  = 2524672;   // [16][64][1024] fp32 (1,048,576)
static const size_t OFF_WDT   = 427520;    // wdT bf16 tiled (4,096,000 fl) - after recur

typedef __attribute__((ext_vector_type(8))) short bf16x8;
typedef __attribute__((ext_vector_type(4))) float f32x4;

__device__ __forceinline__ float bf2f(unsigned int us) { return __uint_as_float(us << 16); }
__device__ __forceinline__ unsigned short f2bf(float f) {
    unsigned int u = __float_as_uint(f);
    return (unsigned short)((u + 0x7fffu + ((u >> 16) & 1u)) >> 16);
}
__device__ __forceinline__ float rcp_fast(float x) { return __builtin_amdgcn_rcpf(x); }
__device__ __forceinline__ float sigm(float x) { return rcp_fast(1.0f + __expf(-x)); }
__device__ __forceinline__ float tanh1(float x) {
    float e = __expf(2.0f * x);
    return 1.0f - 2.0f * rcp_fast(e + 1.0f);
}
__device__ __forceinline__ void cstore(float* p, float v) {
    __hip_atomic_store(p, v, __ATOMIC_RELAXED, __HIP_MEMORY_SCOPE_AGENT);
}
__device__ __forceinline__ float cload(const float* p) {
    return __hip_atomic_load(p, __ATOMIC_RELAXED, __HIP_MEMORY_SCOPE_AGENT);
}

// per-gang barrier (32 arrivals, monotonic epochs, fence-free)
__device__ __forceinline__ void gangbar(int* cnt, int need) {
    __syncthreads();
    if (threadIdx.x == 0) {
        asm volatile("s_waitcnt vmcnt(0) lgkmcnt(0)" ::: "memory");
        __hip_atomic_fetch_add(cnt, 1, __ATOMIC_RELAXED, __HIP_MEMORY_SCOPE_AGENT);
        while (__hip_atomic_load(cnt, __ATOMIC_RELAXED, __HIP_MEMORY_SCOPE_AGENT) < need) {
            __builtin_amdgcn_s_sleep(1);
        }
        asm volatile("" ::: "memory");
    }
    __syncthreads();
}

// ---------------- init: rs, gang counters ----------------
__launch_bounds__(256)
__global__ void init_kernel(float* __restrict__ rs, int* __restrict__ bar) {
    int b = blockIdx.x, u = threadIdx.x;
    if (u < 64) rs[b * 64 + u] = 0.f;
    int idx = b * 256 + u;
    if (idx < 512) bar[idx] = 0;
}

// ---------------- keys^T -> keysT[b][u][s] bf16 ----------------
__launch_bounds__(256)
__global__ void keys_kernel(const float* __restrict__ enc, const float* __restrict__ W2,
                            const float* __restrict__ b2, unsigned short* __restrict__ keysT) {
    __shared__ float els[8 * DE];
    int b = blockIdx.x >> 4, so = blockIdx.x & 15;
    int u = threadIdx.x;
    const float4* src = (const float4*)(enc + ((size_t)b * NS + so * 8) * DE);
    float4* dst = (float4*)els;
    for (int i = u; i < 8 * DE / 4; i += 256) dst[i] = src[i];
    __syncthreads();
    float bias = b2[u];
    float acc[8];
#pragma unroll
    for (int ss = 0; ss < 8; ss++) acc[ss] = bias;
#pragma unroll 4
    for (int d = 0; d < DE; d++) {
        float w = W2[d * NU + u];
#pragma unroll
        for (int ss = 0; ss < 8; ss++) acc[ss] = fmaf(els[ss * DE + d], w, acc[ss]);
    }
    unsigned int w0 = (unsigned int)f2bf(acc[0]) | ((unsigned int)f2bf(acc[1]) << 16);
    unsigned int w1 = (unsigned int)f2bf(acc[2]) | ((unsigned int)f2bf(acc[3]) << 16);
    unsigned int w2 = (unsigned int)f2bf(acc[4]) | ((unsigned int)f2bf(acc[5]) << 16);
    unsigned int w3 = (unsigned int)f2bf(acc[6]) | ((unsigned int)f2bf(acc[7]) << 16);
    *(uint4*)(keysT + ((size_t)b * NU + u) * NS + so * 8) = make_uint4(w0, w1, w2, w3);
}

// ---------------- encWx[b][s][j] = enc[b] @ Wx[0:512] ----------------
// grid 1024 = rowgroup(16) x jtile(64); thread = (jl 16, kg 16 x 32k)
__launch_bounds__(256)
__global__ void encwx_kernel(const float* __restrict__ enc, const float* __restrict__ Wx,
                             float* __restrict__ encWx) {
    __shared__ float wl[DE * 16];  // 32 KB: Wx[:, jt*16 .. +16]
    __shared__ float els[DE];
    __shared__ float zr[16 * 16];
    int rg = blockIdx.x >> 6, jt = blockIdx.x & 63;
    int tid = threadIdx.x, jl = tid & 15, kg = tid >> 4;
    for (int idx = tid; idx < DE * 16; idx += 256)
        wl[idx] = Wx[(size_t)(idx >> 4) * 1024 + jt * 16 + (idx & 15)];
    __syncthreads();
    for (int rr = 0; rr < 128; rr++) {
        int row = rg * 128 + rr;  // (b,s)
        const float* er = enc + (size_t)row * DE;
        els[tid] = er[tid];
        els[256 + tid] = er[256 + tid];
        __syncthreads();
        float acc = 0.f;
#pragma unroll
        for (int i = 0; i < 32; i++)
            acc = fmaf(els[kg * 32 + i], wl[(kg * 32 + i) * 16 + jl], acc);
        zr[kg * 16 + jl] = acc;
        __syncthreads();
        if (tid < 16) {
            float z = 0.f;
#pragma unroll
            for (int g = 0; g < 16; g++) z += zr[g * 16 + tid];
            encWx[(size_t)row * 1024 + jt * 16 + tid] = z;
        }
        __syncthreads();
    }
}

// ---------------- zemb[b][t][j] = emb[tok[b,t]] @ Wx[512:768] + b_lstm ----------------
// grid 256 = rowgroup(8) x jtile(32); thread = (jl 32, kg 8 x 32k)
__launch_bounds__(256)
__global__ void zemb_kernel(const int* __restrict__ dec, const float* __restrict__ emb,
                            const float* __restrict__ Wx, const float* __restrict__ b_lstm,
                            float* __restrict__ zemb) {
    __shared__ float wl[NU * 32];  // 32 KB: Wx[512+k][jt*32 .. +32]
    __shared__ float els[NU];
    __shared__ float zr[8 * 32];
    int rg = blockIdx.x >> 5, jt = blockIdx.x & 31;
    int tid = threadIdx.x, jl = tid & 31, kg = tid >> 5;
    for (int idx = tid; idx < NU * 32; idx += 256)
        wl[idx] = Wx[(size_t)(512 + (idx >> 5)) * 1024 + jt * 32 + (idx & 31)];
    __syncthreads();
    for (int rr = 0; rr < 128; rr++) {
        int row = rg * 128 + rr;  // (b,t)
        int b = row >> 6, t = row & 63;
        int tok = dec[b * NT + t];
        tok = (tok < 0) ? 0 : (tok >= NV ? NV - 1 : tok);
        els[tid] = emb[(size_t)tok * NU + tid];
        __syncthreads();
        float acc = 0.f;
#pragma unroll
        for (int i = 0; i < 32; i++)
            acc = fmaf(els[kg * 32 + i], wl[(kg * 32 + i) * 32 + jl], acc);
        zr[kg * 32 + jl] = acc;
        __syncthreads();
        if (tid < 32) {
            float z = 0.f;
#pragma unroll
            for (int g = 0; g < 8; g++) z += zr[g * 32 + tid];
            zemb[(size_t)row * 1024 + jt * 32 + tid] = z + b_lstm[jt * 32 + tid];
        }
        __syncthreads();
    }
}

// ---------------- Wd -> fragment-tiled bf16 (runs AFTER recur) ----------------
__launch_bounds__(256)
__global__ void wdtile_kernel(const float* __restrict__ Wd, unsigned short* __restrict__ wdT) {
    int id = blockIdx.x * 256 + threadIdx.x;
    int l = id & 63, c16 = (id >> 6) & 7, ks = (id >> 9) & 7, p = id >> 12;
    int v = p * 128 + c16 * 16 + (l & 15);
    int k0 = ks * 32 + (l >> 4) * 8;
    unsigned int wout[4];
#pragma unroll
    for (int jj = 0; jj < 4; jj++) {
        unsigned int lo = f2bf(Wd[(size_t)(k0 + 2 * jj) * NV + v]);
        unsigned int hi = f2bf(Wd[(size_t)(k0 + 2 * jj + 1) * NV + v]);
        wout[jj] = lo | (hi << 16);
    }
    *(uint4*)(wdT + (size_t)id * 8) = make_uint4(wout[0], wout[1], wout[2], wout[3]);
}

// ---------------- persistent recurrence: 1 barrier/step ----------------
__launch_bounds__(256, 1)
__global__ void recur_kernel(const float* __restrict__ W1, const float* __restrict__ b1,
                             const float* __restrict__ Va, const float* __restrict__ bV,
                             const float* __restrict__ Wh, const float* __restrict__ h0,
                             const float* __restrict__ c0,
                             const unsigned short* __restrict__ keysT,
                             const float* __restrict__ encWx, const float* __restrict__ zemb,
                             float* __restrict__ zfull, unsigned short* __restrict__ Hb,
                             int* __restrict__ bar) {
    __shared__ float hl[NU];
    __shared__ float qv[NU];
    __shared__ float scp[NU];
    __shared__ float red[NS];
    __shared__ float attn[NS];
    __shared__ float xcat[384];
    __shared__ float zred[4 * 64];

    int tid = threadIdx.x;
    int gang = blockIdx.x & 7;
    int r = blockIdx.x >> 3;          // 0..31
    int b = gang * 2 + (r & 1);
    int jsl = (r >> 1) * 64;          // 64-column z slice
    int* cnt = bar + gang * 64;
    int u = tid;
    int jg = jsl + (tid & 63);
    int kg = tid >> 6;                // wave id = k-group (96 k each)

    float c_reg = c0[b * NU + u];

    // one-time: pin 96 weights/thread in registers
    const float* wsrc = encWx + (size_t)b * 128 * 1024 + jg;
    float wreg[96];
#pragma unroll
    for (int i = 0; i < 96; i++) {
        int k = kg * 96 + i;
        wreg[i] = (k < 128) ? wsrc[(size_t)k * 1024] : Wh[(size_t)(k - 128) * 1024 + jg];
    }

    for (int it = 0; it <= NT; ++it) {
        float hn;
        if (it > 0) {
            const float* zb = zfull + (size_t)((((it - 1) & 1) * NB) + b) * 1024;
            float zi = cload(zb + u);
            float zf = cload(zb + 256 + u);
            float zg = cload(zb + 512 + u);
            float zo = cload(zb + 768 + u);
            float cn = sigm(zf) * c_reg + sigm(zi) * tanh1(zg);
            c_reg = cn;
            hn = sigm(zo) * tanh1(cn);
            if (r < 2) {  // one block per b writes Hb
                int rr = (it - 1) * NB + b;
                int mp = rr >> 7, lr = rr & 127;
                int chunk = ((u >> 5) * 8 + (lr >> 4)) * 64 + ((u >> 3) & 3) * 16 + (lr & 15);
                Hb[(size_t)mp * 32768 + chunk * 8 + (u & 7)] = f2bf(hn);
            }
        } else {
            hn = h0[b * NU + u];
        }
        hl[u] = hn;
        __syncthreads();
        if (it == NT) break;

        // q = h @ W1 + b1 (replicated; W1 L2-resident)
        float a = b1[u];
#pragma unroll 8
        for (int d = 0; d < NU; d++) a = fmaf(hl[d], W1[d * NU + u], a);
        qv[u] = a;
        __syncthreads();

        // scores: thread = (s, u-half)
        int s = tid & 127, uh = tid >> 7;
        const unsigned short* kp = keysT + ((size_t)b * NU + uh * 128) * NS + s;
        float sc = 0.f;
#pragma unroll 4
        for (int uu = 0; uu < 128; uu++)
            sc = fmaf(tanh1(qv[uh * 128 + uu] + bf2f(kp[(size_t)uu * NS])), Va[uh * 128 + uu], sc);
        scp[uh * NS + s] = sc;
        __syncthreads();
        float scfull = 0.f, p = 0.f;
        if (tid < NS) {
            scfull = scp[tid] + scp[NS + tid] + bV[0];
            red[tid] = scfull;
        }
        __syncthreads();
        for (int off = 64; off >= 1; off >>= 1) {
            if (tid < off) red[tid] = fmaxf(red[tid], red[tid + off]);
            __syncthreads();
        }
        float m = red[0];
        __syncthreads();
        if (tid < NS) {
            p = __expf(scfull - m);
            red[tid] = p;
        }
        __syncthreads();
        for (int off = 64; off >= 1; off >>= 1) {
            if (tid < off) red[tid] += red[tid + off];
            __syncthreads();
        }
        float tot = red[0];
        if (tid < NS) attn[tid] = p / tot;
        __syncthreads();

        // xcat = [attn(128) | h(256)]
        xcat[tid] = (tid < 128) ? attn[tid] : hl[tid - 128];
        if (tid < 128) xcat[256 + tid] = hl[128 + tid];
        __syncthreads();

        // z slice: 96 register-weight FMAs per thread
        float zacc = 0.f;
        const float* xk = xcat + kg * 96;
#pragma unroll
        for (int i = 0; i < 96; i++) zacc = fmaf(wreg[i], xk[i], zacc);
        zred[kg * 64 + (tid & 63)] = zacc;
        __syncthreads();
        if (tid < 64) {
            float z = zred[tid] + zred[64 + tid] + zred[128 + tid] + zred[192 + tid] +
                      zemb[((size_t)b * NT + it) * 1024 + jsl + tid];
            cstore(&zfull[(size_t)((it & 1) * NB + b) * 1024 + jsl + tid], z);
        }
        gangbar(cnt, (it + 1) * GBLK);
    }
}

// ---------------- batched vocab GEMM + exp + rowsum ----------------
__launch_bounds__(256)
__global__ void gemm_kernel(const unsigned short* __restrict__ Hb,
                            const unsigned short* __restrict__ wdT,
                            const float* __restrict__ bd, float* __restrict__ out,
                            float* __restrict__ rs) {
    int w = (blockIdx.x & 7) * 250 + (blockIdx.x >> 3);
    int np = w >> 3, mp = w & 7;
    int wave = threadIdx.x >> 6, l = threadIdx.x & 63;
    int wm = wave >> 1, wn = wave & 1;
    const bf16x8* A = (const bf16x8*)Hb + (size_t)mp * 4096;
    const bf16x8* B = (const bf16x8*)wdT + (size_t)np * 4096;
    f32x4 acc[4][4];
#pragma unroll
    for (int mf = 0; mf < 4; mf++)
#pragma unroll
        for (int nf = 0; nf < 4; nf++) acc[mf][nf] = (f32x4){0.f, 0.f, 0.f, 0.f};
#pragma unroll
    for (int ks = 0; ks < 8; ks++) {
        bf16x8 av[4], bv[4];
#pragma unroll
        for (int mf = 0; mf < 4; mf++) av[mf] = A[(ks * 8 + wm * 4 + mf) * 64 + l];
#pragma unroll
        for (int nf = 0; nf < 4; nf++) bv[nf] = B[(ks * 8 + wn * 4 + nf) * 64 + l];
#pragma unroll
        for (int mf = 0; mf < 4; mf++)
#pragma unroll
            for (int nf = 0; nf < 4; nf++)
                acc[mf][nf] =
                    __builtin_amdgcn_mfma_f32_16x16x32_bf16(av[mf], bv[nf], acc[mf][nf], 0, 0, 0);
    }
    int colg = np * 128 + wn * 64;
    int rowg = mp * 128 + wm * 64;
#pragma unroll
    for (int mf = 0; mf < 4; mf++) {
        float rloc[4] = {0.f, 0.f, 0.f, 0.f};
#pragma unroll
        for (int nf = 0; nf < 4; nf++) {
            int col = colg + nf * 16 + (l & 15);
            float bdv = bd[col];
#pragma unroll
            for (int reg = 0; reg < 4; reg++) {
                int rr = rowg + mf * 16 + (l >> 4) * 4 + reg;  // rr = t*16 + b
                float p = __expf(acc[mf][nf][reg] + bdv);
                out[(size_t)((rr & 15) * NT + (rr >> 4)) * NV + col] = p;
                rloc[reg] += p;
            }
        }
#pragma unroll
        for (int reg = 0; reg < 4; reg++) {
            float v = rloc[reg];
            v += __shfl_xor(v, 1);
            v += __shfl_xor(v, 2);
            v += __shfl_xor(v, 4);
            v += __shfl_xor(v, 8);
            if ((l & 15) == 0) atomicAdd(&rs[rowg + mf * 16 + (l >> 4) * 4 + reg], v);
        }
    }
}

// ---------------- final softmax normalization ----------------
__launch_bounds__(256)
__global__ void scale_kernel(float* __restrict__ out, const float* __restrict__ rs) {
    int o = blockIdx.x;  // out row = b*64 + t
    int b = o >> 6, t = o & 63;
    float rinv = 1.0f / rs[t * NB + b];
    float4* op = (float4*)(out + (size_t)o * NV);
    for (int i = threadIdx.x; i < NV / 4; i += 256) {
        float4 v = op[i];
        v.x *= rinv; v.y *= rinv; v.z *= rinv; v.w *= rinv;
        op[i] = v;
    }
}

extern "C" void kernel_launch(void* const* d_in, const int* in_sizes, int n_in,
                              void* d_out, int out_size, void* d_ws, size_t ws_size,
                              hipStream_t stream) {
    const int* dec = (const int*)d_in[0];
    const float* enc = (const float*)d_in[1];
    const float* h0 = (const float*)d_in[2];
    const float* c0 = (const float*)d_in[3];
    const float* emb = (const float*)d_in[4];
    const float* W1 = (const float*)d_in[5];
    const float* b1 = (const float*)d_in[6];
    const float* W2 = (const float*)d_in[7];
    const float* b2 = (const float*)d_in[8];
    const float* Va = (const float*)d_in[9];
    const float* bV = (const float*)d_in[10];
    const float* Wx = (const float*)d_in[11];
    const float* Wh = (const float*)d_in[12];
    const float* b_lstm = (const float*)d_in[13];
    const float* Wd = (const float*)d_in[14];
    const float* bd = (const float*)d_in[15];
    float* out = (float*)d_out;
    float* ws = (float*)d_ws;

    unsigned short* keysT = (unsigned short*)(ws + OFF_KEYS);
    float* zfull = ws + OFF_ZF;
    float* ws_rs = ws + OFF_RS;
    int* bar = (int*)(ws + OFF_BAR);
    unsigned short* Hb = (unsigned short*)(ws + OFF_HBUF);
    float* encWx = ws + OFF_ENCWX;
    float* zemb = ws + OFF_ZEMB;
    unsigned short* wdT = (unsigned short*)(ws + OFF_WDT);

    init_kernel<<<16, 256, 0, stream>>>(ws_rs, bar);
    keys_kernel<<<256, 256, 0, stream>>>(enc, W2, b2, keysT);
    encwx_kernel<<<1024, 256, 0, stream>>>(enc, Wx, encWx);
    zemb_kernel<<<256, 256, 0, stream>>>(dec, emb, Wx, b_lstm, zemb);
    recur_kernel<<<256, 256, 0, stream>>>(W1, b1, Va, bV, Wh, h0, c0, keysT, encWx, zemb,
                                          zfull, Hb, bar);
    wdtile_kernel<<<4000, 256, 0, stream>>>(Wd, wdT);  // overwrites encWx/zemb region
    gemm_kernel<<<2000, 256, 0, stream>>>(Hb, wdT, bd, out, ws_rs);
    scale_kernel<<<1024, 256, 0, stream>>>(out, ws_rs);
}

// Round 9
// 1038.618 us; speedup vs baseline: 2.6521x; 1.4023x over previous
//
#include <hip/hip_runtime.h>

// Decoder, B=16, T=64, S=128, D_ENC=512, U=256, V=32000.
// Round 9: latency-hiding recurrence.
//   - 16 independent gangs (one per batch), 8 blocks x 512 threads each
//   - 2 waves/SIMD TLP; z-weights register-pinned (fp32); W1 bf16-packed
//   - wave-shuffle softmax reductions; 8-arrival fence-free gang barrier
//   - prologue GEMVs (keys/encwx/zemb) restructured: coalesced weight reads,
//     uniform (scalar) activation reads, 16-32 rows per thread in registers
// Epilogue: bf16 MFMA vocab GEMM + exp + rowsum, deferred softmax scale.

#define NB 16
#define NT 64
#define NS 128
#define DE 512
#define NU 256
#define NV 32000

// ws layout (floats); total 4,524,032 fl = 18.10 MB (<= 18.32 proven in R4-6)
static const size_t OFF_KEYS  = 0;          // keysT bf16 [16][256][128] -> 262144
static const size_t OFF_ZF    = 262144;     // zfull dbuf [2][16][1024] -> 32768
static const size_t OFF_RS    = 294912;     // rowsums [1024]
static const size_t OFF_BAR   = 295936;     // 16 gang counters * 64 ints
static const size_t OFF_HBUF  = 296960;     // Hb fragment-tiled bf16 -> 131072
static const size_t OFF_W1P   = 428032;     // W1 bf16-packed [128][256] uint -> 32768
static const size_t OFF_ENCWX = 460800;     // [16*128][1024] fp32 -> 2097152
static const size_t OFF_ZEMB  = 2557952;    // [16*64][1024] fp32 -> 1048576
static const size_t OFF_WDT   = 428032;     // wdT bf16 tiled (4096000 fl), after recur

typedef __attribute__((ext_vector_type(8))) short bf16x8;
typedef __attribute__((ext_vector_type(4))) float f32x4;

__device__ __forceinline__ float bf2f(unsigned int us) { return __uint_as_float(us << 16); }
__device__ __forceinline__ unsigned short f2bf(float f) {
    unsigned int u = __float_as_uint(f);
    return (unsigned short)((u + 0x7fffu + ((u >> 16) & 1u)) >> 16);
}
__device__ __forceinline__ float rcp_fast(float x) { return __builtin_amdgcn_rcpf(x); }
__device__ __forceinline__ float sigm(float x) { return rcp_fast(1.0f + __expf(-x)); }
__device__ __forceinline__ float tanh1(float x) {
    float e = __expf(2.0f * x);
    return 1.0f - 2.0f * rcp_fast(e + 1.0f);
}
__device__ __forceinline__ void cstore(float* p, float v) {
    __hip_atomic_store(p, v, __ATOMIC_RELAXED, __HIP_MEMORY_SCOPE_AGENT);
}
__device__ __forceinline__ float cload(const float* p) {
    return __hip_atomic_load(p, __ATOMIC_RELAXED, __HIP_MEMORY_SCOPE_AGENT);
}

// per-gang barrier (8 arrivals, monotonic epochs, fence-free)
__device__ __forceinline__ void gangbar(int* cnt, int need) {
    __syncthreads();
    if (threadIdx.x == 0) {
        asm volatile("s_waitcnt vmcnt(0) lgkmcnt(0)" ::: "memory");
        __hip_atomic_fetch_add(cnt, 1, __ATOMIC_RELAXED, __HIP_MEMORY_SCOPE_AGENT);
        while (__hip_atomic_load(cnt, __ATOMIC_RELAXED, __HIP_MEMORY_SCOPE_AGENT) < need) {
            __builtin_amdgcn_s_sleep(1);
        }
        asm volatile("" ::: "memory");
    }
    __syncthreads();
}

// ---------------- init ----------------
__launch_bounds__(256)
__global__ void init_kernel(float* __restrict__ rs, int* __restrict__ bar) {
    int idx = blockIdx.x * 256 + threadIdx.x;
    if (idx < 1024) rs[idx] = 0.f;
    if (idx < 1024) bar[idx] = 0;
}

// ---------------- W1 -> bf16-packed (d-pairs) ----------------
__launch_bounds__(256)
__global__ void w1pack_kernel(const float* __restrict__ W1, unsigned int* __restrict__ W1p) {
    int id = blockIdx.x * 256 + threadIdx.x;  // 32768
    int dp = id >> 8, u = id & 255;
    unsigned int lo = f2bf(W1[(size_t)(2 * dp) * NU + u]);
    unsigned int hi = f2bf(W1[(size_t)(2 * dp + 1) * NU + u]);
    W1p[id] = lo | (hi << 16);
}

// ---------------- keysT[b][u][s] = (enc @ W2 + b2)^T, bf16 ----------------
// 128 blocks = b(16) x sg(8, 16 s-rows); thread = u
__launch_bounds__(256)
__global__ void keys_kernel(const float* __restrict__ enc, const float* __restrict__ W2,
                            const float* __restrict__ b2, unsigned short* __restrict__ keysT) {
    int b = blockIdx.x >> 3, sg = blockIdx.x & 7;
    int u = threadIdx.x;
    float acc[16];
    float bias = b2[u];
#pragma unroll
    for (int r = 0; r < 16; r++) acc[r] = bias;
    const float4* e4 = (const float4*)(enc + ((size_t)b * NS + sg * 16) * DE);
    const float* wp = W2 + u;
    for (int k4 = 0; k4 < DE / 4; k4++) {
        float w0 = wp[(size_t)(k4 * 4 + 0) * NU];
        float w1 = wp[(size_t)(k4 * 4 + 1) * NU];
        float w2v = wp[(size_t)(k4 * 4 + 2) * NU];
        float w3v = wp[(size_t)(k4 * 4 + 3) * NU];
#pragma unroll
        for (int r = 0; r < 16; r++) {
            float4 e = e4[(size_t)r * (DE / 4) + k4];  // wave-uniform -> scalar
            acc[r] = fmaf(e.x, w0, fmaf(e.y, w1, fmaf(e.z, w2v, fmaf(e.w, w3v, acc[r]))));
        }
    }
    unsigned int ow[8];
#pragma unroll
    for (int i = 0; i < 8; i++)
        ow[i] = (unsigned int)f2bf(acc[2 * i]) | ((unsigned int)f2bf(acc[2 * i + 1]) << 16);
    uint4* dst = (uint4*)(keysT + ((size_t)b * NU + u) * NS + sg * 16);
    dst[0] = make_uint4(ow[0], ow[1], ow[2], ow[3]);
    dst[1] = make_uint4(ow[4], ow[5], ow[6], ow[7]);
}

// ---------------- encWx[(b,s)][j] = enc @ Wx[0:512] ----------------
// 256 blocks = rg(64, 32 rows) x jq(4); thread = j-lane
__launch_bounds__(256)
__global__ void encwx_kernel(const float* __restrict__ enc, const float* __restrict__ Wx,
                             float* __restrict__ encWx) {
    int rg = blockIdx.x >> 2, jq = blockIdx.x & 3;
    int j = jq * 256 + threadIdx.x;
    float acc[32];
#pragma unroll
    for (int r = 0; r < 32; r++) acc[r] = 0.f;
    const float4* e4 = (const float4*)(enc + (size_t)rg * 32 * DE);
    const float* wp = Wx + j;
    for (int k4 = 0; k4 < DE / 4; k4++) {
        float w0 = wp[(size_t)(k4 * 4 + 0) * 1024];
        float w1 = wp[(size_t)(k4 * 4 + 1) * 1024];
        float w2v = wp[(size_t)(k4 * 4 + 2) * 1024];
        float w3v = wp[(size_t)(k4 * 4 + 3) * 1024];
#pragma unroll
        for (int r = 0; r < 32; r++) {
            float4 e = e4[(size_t)r * (DE / 4) + k4];  // wave-uniform -> scalar
            acc[r] = fmaf(e.x, w0, fmaf(e.y, w1, fmaf(e.z, w2v, fmaf(e.w, w3v, acc[r]))));
        }
    }
#pragma unroll
    for (int r = 0; r < 32; r++) encWx[(size_t)(rg * 32 + r) * 1024 + j] = acc[r];
}

// ---------------- zemb[(b,t)][j] = emb[tok] @ Wx[512:768] + b_lstm ----------------
// 128 blocks = rg(32, 32 rows) x jq(4); thread = j-lane
__launch_bounds__(256)
__global__ void zemb_kernel(const int* __restrict__ dec, const float* __restrict__ emb,
                            const float* __restrict__ Wx, const float* __restrict__ b_lstm,
                            float* __restrict__ zemb) {
    int rg = blockIdx.x >> 2, jq = blockIdx.x & 3;
    int j = jq * 256 + threadIdx.x;
    int tokr[32];
#pragma unroll
    for (int r = 0; r < 32; r++) {
        int row = rg * 32 + r;
        int tok = dec[(row >> 6) * NT + (row & 63)];
        tokr[r] = (tok < 0) ? 0 : (tok >= NV ? NV - 1 : tok);
    }
    float acc[32];
    float bias = b_lstm[j];
#pragma unroll
    for (int r = 0; r < 32; r++) acc[r] = bias;
    const float* wp = Wx + (size_t)512 * 1024 + j;
    for (int k4 = 0; k4 < NU / 4; k4++) {
        float w0 = wp[(size_t)(k4 * 4 + 0) * 1024];
        float w1 = wp[(size_t)(k4 * 4 + 1) * 1024];
        float w2v = wp[(size_t)(k4 * 4 + 2) * 1024];
        float w3v = wp[(size_t)(k4 * 4 + 3) * 1024];
#pragma unroll
        for (int r = 0; r < 32; r++) {
            float4 e = ((const float4*)(emb + (size_t)tokr[r] * NU))[k4];  // uniform
            acc[r] = fmaf(e.x, w0, fmaf(e.y, w1, fmaf(e.z, w2v, fmaf(e.w, w3v, acc[r]))));
        }
    }
#pragma unroll
    for (int r = 0; r < 32; r++) zemb[(size_t)(rg * 32 + r) * 1024 + j] = acc[r];
}

// ---------------- Wd -> fragment-tiled bf16 (after recur) ----------------
__launch_bounds__(256)
__global__ void wdtile_kernel(const float* __restrict__ Wd, unsigned short* __restrict__ wdT) {
    int id = blockIdx.x * 256 + threadIdx.x;
    int l = id & 63, c16 = (id >> 6) & 7, ks = (id >> 9) & 7, p = id >> 12;
    int v = p * 128 + c16 * 16 + (l & 15);
    int k0 = ks * 32 + (l >> 4) * 8;
    unsigned int wout[4];
#pragma unroll
    for (int jj = 0; jj < 4; jj++) {
        unsigned int lo = f2bf(Wd[(size_t)(k0 + 2 * jj) * NV + v]);
        unsigned int hi = f2bf(Wd[(size_t)(k0 + 2 * jj + 1) * NV + v]);
        wout[jj] = lo | (hi << 16);
    }
    *(uint4*)(wdT + (size_t)id * 8) = make_uint4(wout[0], wout[1], wout[2], wout[3]);
}

// ---------------- persistent recurrence: 16 gangs x 8 blocks x 512 thr ----------------
__launch_bounds__(512, 2)
__global__ void recur_kernel(const float* __restrict__ b1, const float* __restrict__ Va,
                             const float* __restrict__ bV, const float* __restrict__ Wh,
                             const float* __restrict__ h0, const float* __restrict__ c0,
                             const unsigned short* __restrict__ keysT,
                             const unsigned int* __restrict__ W1p,
                             const float* __restrict__ encWx, const float* __restrict__ zemb,
                             float* __restrict__ zfull, unsigned short* __restrict__ Hb,
                             int* __restrict__ bar) {
    __shared__ float hl[NU];
    __shared__ float qv[NU];
    __shared__ float qred[512];
    __shared__ float scp[512];
    __shared__ float red[132];
    __shared__ float xcat[384];
    __shared__ float zred[512];

    int tid = threadIdx.x;
    int b = blockIdx.x & 15;          // gang = batch (XCD-local: all blocks == b mod 8... b&7)
    int r = blockIdx.x >> 4;          // 0..7 -> j-slice r*128
    int* cnt = bar + b * 64;
    int jl = tid & 127, kg = tid >> 7;  // j-lane, k-group (4 x 96)
    int j = r * 128 + jl;

    float c_reg = (tid < NU) ? c0[b * NU + tid] : 0.f;
    float bV0 = bV[0];

    // pin 96 z-weights per thread (fp32): k<128 -> attn part (encWx), else h part (Wh)
    float wreg[96];
    {
        const float* ew = encWx + (size_t)b * 128 * 1024 + j;
        const float* wh = Wh + j;
#pragma unroll
        for (int i = 0; i < 96; i++) {
            int k = kg * 96 + i;
            wreg[i] = (k < 128) ? ew[(size_t)k * 1024] : wh[(size_t)(k - 128) * 1024];
        }
    }

    for (int it = 0; it <= NT; ++it) {
        // ---- gates (tid<256) ----
        if (tid < NU) {
            float hn;
            if (it > 0) {
                const float* zb = zfull + (size_t)(((it - 1) & 1) * NB + b) * 1024;
                float zi = cload(zb + tid);
                float zf = cload(zb + 256 + tid);
                float zg = cload(zb + 512 + tid);
                float zo = cload(zb + 768 + tid);
                float cn = sigm(zf) * c_reg + sigm(zi) * tanh1(zg);
                c_reg = cn;
                hn = sigm(zo) * tanh1(cn);
                if (r == 0) {
                    int rr = (it - 1) * NB + b;
                    int mp = rr >> 7, lr = rr & 127;
                    int chunk = ((tid >> 5) * 8 + (lr >> 4)) * 64 + ((tid >> 3) & 3) * 16 + (lr & 15);
                    Hb[(size_t)mp * 32768 + chunk * 8 + (tid & 7)] = f2bf(hn);
                }
            } else {
                hn = h0[b * NU + tid];
            }
            hl[tid] = hn;
        }
        __syncthreads();
        if (it == NT) break;

        // ---- q = h @ W1(bf16) + b1 : 512 thr = 256 u x 2 d-halves ----
        {
            int u0 = tid & 255, dh = tid >> 8;
            const unsigned int* wp = W1p + dh * 64 * 256 + u0;
            float a = 0.f;
#pragma unroll 8
            for (int dp = 0; dp < 64; dp++) {
                unsigned int w = wp[(size_t)dp * 256];
                a = fmaf(bf2f(w & 0xffffu), hl[(dh * 64 + dp) * 2], a);
                a = fmaf(bf2f(w >> 16), hl[(dh * 64 + dp) * 2 + 1], a);
            }
            qred[dh * 256 + u0] = a;
        }
        __syncthreads();
        if (tid < NU) qv[tid] = qred[tid] + qred[256 + tid] + b1[tid];
        __syncthreads();

        // ---- scores: 512 thr = 128 s x 4 u-groups(64) ----
        int s = tid & 127, ug = tid >> 7;
        {
            const unsigned short* kp = keysT + ((size_t)b * NU + ug * 64) * NS + s;
            float sc = 0.f;
#pragma unroll 4
            for (int uu = 0; uu < 64; uu++)
                sc = fmaf(tanh1(qv[ug * 64 + uu] + bf2f(kp[(size_t)uu * NS])),
                          Va[ug * 64 + uu], sc);
            scp[ug * 128 + s] = sc;
        }
        __syncthreads();
        float sfull = 0.f, p = 0.f;
        if (tid < 128) {
            sfull = scp[tid] + scp[128 + tid] + scp[256 + tid] + scp[384 + tid] + bV0;
            red[tid] = sfull;
        }
        __syncthreads();
        if (tid < 64) {
            float v = fmaxf(red[tid], red[tid + 64]);
#pragma unroll
            for (int off = 32; off >= 1; off >>= 1) v = fmaxf(v, __shfl_xor(v, off, 64));
            if (tid == 0) red[128] = v;
        }
        __syncthreads();
        float m = red[128];
        if (tid < 128) {
            p = __expf(sfull - m);
            red[tid] = p;
        }
        __syncthreads();
        if (tid < 64) {
            float v = red[tid] + red[tid + 64];
#pragma unroll
            for (int off = 32; off >= 1; off >>= 1) v += __shfl_xor(v, off, 64);
            if (tid == 0) red[129] = v;
        }
        __syncthreads();
        float tot = red[129];
        // xcat = [attn(128) | h(256)]
        if (tid < 128) xcat[tid] = p / tot;
        else if (tid < 384) xcat[tid] = hl[tid - 128];
        __syncthreads();

        // ---- z slice: 96 register-weight FMAs ----
        float zacc = 0.f;
        const float* xk = xcat + kg * 96;
#pragma unroll
        for (int i = 0; i < 96; i++) zacc = fmaf(wreg[i], xk[i], zacc);
        zred[kg * 128 + jl] = zacc;
        __syncthreads();
        if (tid < 128) {
            float z = zred[tid] + zred[128 + tid] + zred[256 + tid] + zred[384 + tid] +
                      zemb[((size_t)b * NT + it) * 1024 + r * 128 + tid];
            cstore(&zfull[(size_t)((it & 1) * NB + b) * 1024 + r * 128 + tid], z);
        }
        gangbar(cnt, (it + 1) * 8);
    }
}

// ---------------- batched vocab GEMM + exp + rowsum ----------------
__launch_bounds__(256)
__global__ void gemm_kernel(const unsigned short* __restrict__ Hb,
                            const unsigned short* __restrict__ wdT,
                            const float* __restrict__ bd, float* __restrict__ out,
                            float* __restrict__ rs) {
    int w = (blockIdx.x & 7) * 250 + (blockIdx.x >> 3);
    int np = w >> 3, mp = w & 7;
    int wave = threadIdx.x >> 6, l = threadIdx.x & 63;
    int wm = wave >> 1, wn = wave & 1;
    const bf16x8* A = (const bf16x8*)Hb + (size_t)mp * 4096;
    const bf16x8* B = (const bf16x8*)wdT + (size_t)np * 4096;
    f32x4 acc[4][4];
#pragma unroll
    for (int mf = 0; mf < 4; mf++)
#pragma unroll
        for (int nf = 0; nf < 4; nf++) acc[mf][nf] = (f32x4){0.f, 0.f, 0.f, 0.f};
#pragma unroll
    for (int ks = 0; ks < 8; ks++) {
        bf16x8 av[4], bv[4];
#pragma unroll
        for (int mf = 0; mf < 4; mf++) av[mf] = A[(ks * 8 + wm * 4 + mf) * 64 + l];
#pragma unroll
        for (int nf = 0; nf < 4; nf++) bv[nf] = B[(ks * 8 + wn * 4 + nf) * 64 + l];
#pragma unroll
        for (int mf = 0; mf < 4; mf++)
#pragma unroll
            for (int nf = 0; nf < 4; nf++)
                acc[mf][nf] =
                    __builtin_amdgcn_mfma_f32_16x16x32_bf16(av[mf], bv[nf], acc[mf][nf], 0, 0, 0);
    }
    int colg = np * 128 + wn * 64;
    int rowg = mp * 128 + wm * 64;
#pragma unroll
    for (int mf = 0; mf < 4; mf++) {
        float rloc[4] = {0.f, 0.f, 0.f, 0.f};
#pragma unroll
        for (int nf = 0; nf < 4; nf++) {
            int col = colg + nf * 16 + (l & 15);
            float bdv = bd[col];
#pragma unroll
            for (int reg = 0; reg < 4; reg++) {
                int rr = rowg + mf * 16 + (l >> 4) * 4 + reg;  // rr = t*16 + b
                float p = __expf(acc[mf][nf][reg] + bdv);
                out[(size_t)((rr & 15) * NT + (rr >> 4)) * NV + col] = p;
                rloc[reg] += p;
            }
        }
#pragma unroll
        for (int reg = 0; reg < 4; reg++) {
            float v = rloc[reg];
            v += __shfl_xor(v, 1);
            v += __shfl_xor(v, 2);
            v += __shfl_xor(v, 4);
            v += __shfl_xor(v, 8);
            if ((l & 15) == 0) atomicAdd(&rs[rowg + mf * 16 + (l >> 4) * 4 + reg], v);
        }
    }
}

// ---------------- final softmax normalization ----------------
__launch_bounds__(256)
__global__ void scale_kernel(float* __restrict__ out, const float* __restrict__ rs) {
    int o = blockIdx.x;  // out row = b*64 + t
    int b = o >> 6, t = o & 63;
    float rinv = 1.0f / rs[t * NB + b];
    float4* op = (float4*)(out + (size_t)o * NV);
    for (int i = threadIdx.x; i < NV / 4; i += 256) {
        float4 v = op[i];
        v.x *= rinv; v.y *= rinv; v.z *= rinv; v.w *= rinv;
        op[i] = v;
    }
}

extern "C" void kernel_launch(void* const* d_in, const int* in_sizes, int n_in,
                              void* d_out, int out_size, void* d_ws, size_t ws_size,
                              hipStream_t stream) {
    const int* dec = (const int*)d_in[0];
    const float* enc = (const float*)d_in[1];
    const float* h0 = (const float*)d_in[2];
    const float* c0 = (const float*)d_in[3];
    const float* emb = (const float*)d_in[4];
    const float* W1 = (const float*)d_in[5];
    const float* b1 = (const float*)d_in[6];
    const float* W2 = (const float*)d_in[7];
    const float* b2 = (const float*)d_in[8];
    const float* Va = (const float*)d_in[9];
    const float* bV = (const float*)d_in[10];
    const float* Wx = (const float*)d_in[11];
    const float* Wh = (const float*)d_in[12];
    const float* b_lstm = (const float*)d_in[13];
    const float* Wd = (const float*)d_in[14];
    const float* bd = (const float*)d_in[15];
    float* out = (float*)d_out;
    float* ws = (float*)d_ws;

    unsigned short* keysT = (unsigned short*)(ws + OFF_KEYS);
    float* zfull = ws + OFF_ZF;
    float* ws_rs = ws + OFF_RS;
    int* bar = (int*)(ws + OFF_BAR);
    unsigned short* Hb = (unsigned short*)(ws + OFF_HBUF);
    unsigned int* W1p = (unsigned int*)(ws + OFF_W1P);
    float* encWx = ws + OFF_ENCWX;
    float* zemb = ws + OFF_ZEMB;
    unsigned short* wdT = (unsigned short*)(ws + OFF_WDT);

    init_kernel<<<4, 256, 0, stream>>>(ws_rs, bar);
    w1pack_kernel<<<128, 256, 0, stream>>>(W1, W1p);
    keys_kernel<<<128, 256, 0, stream>>>(enc, W2, b2, keysT);
    encwx_kernel<<<256, 256, 0, stream>>>(enc, Wx, encWx);
    zemb_kernel<<<128, 256, 0, stream>>>(dec, emb, Wx, b_lstm, zemb);
    recur_kernel<<<128, 512, 0, stream>>>(b1, Va, bV, Wh, h0, c0, keysT, W1p, encWx, zemb,
                                          zfull, Hb, bar);
    wdtile_kernel<<<4000, 256, 0, stream>>>(Wd, wdT);  // overwrites W1p/encWx/zemb
    gemm_kernel<<<2000, 256, 0, stream>>>(Hb, wdT, bd, out, ws_rs);
    scale_kernel<<<1024, 256, 0, stream>>>(out, ws_rs);
}

// Round 10
// 754.741 us; speedup vs baseline: 3.6496x; 1.3761x over previous
//
#include <hip/hip_runtime.h>

// Decoder, B=16, T=64, S=128, D_ENC=512, U=256, V=32000.
// Round 10: recurrence = 16 gangs (1/batch) x 8 blocks x 512 thr, 1 block/CU
// (LDS-forced), register-pinned z-weights, f16 W1 dot2, no-max softmax,
// zemb prefetch. Prologue fused into 1 kernel. Epilogue: wdtile + two-pass
// MFMA vocab GEMM (pass1 exp+rowsum, pass2 normalized write) - no scale pass.

#define NB 16
#define NT 64
#define NS 128
#define DE 512
#define NU 256
#define NV 32000

// ws layout (floats); total 4,524,032 fl = 18.10 MB (proven available)
static const size_t OFF_KEYS  = 0;          // keysT bf16 [16][256][128] -> 262144
static const size_t OFF_ZF    = 262144;     // zfull dbuf [2][16][1024] -> 32768
static const size_t OFF_RS    = 294912;     // rowsums [1024]
static const size_t OFF_BAR   = 295936;     // 16 gang counters * 64 ints
static const size_t OFF_HBUF  = 296960;     // Hb fragment-tiled bf16 -> 131072
static const size_t OFF_W1P   = 428032;     // W1 f16-packed [128][256] uint -> 32768
static const size_t OFF_ENCWX = 460800;     // [16*128][1024] fp32 -> 2097152
static const size_t OFF_ZEMB  = 2557952;    // [16*64][1024] fp32 -> 1048576
static const size_t OFF_WDT   = 428032;     // wdT bf16 tiled (4096000 fl), after recur

typedef __attribute__((ext_vector_type(8))) short bf16x8;
typedef __attribute__((ext_vector_type(4))) float f32x4;
typedef __attribute__((ext_vector_type(2))) _Float16 f16x2;

__device__ __forceinline__ float bf2f(unsigned int us) { return __uint_as_float(us << 16); }
__device__ __forceinline__ unsigned short f2bf(float f) {
    unsigned int u = __float_as_uint(f);
    return (unsigned short)((u + 0x7fffu + ((u >> 16) & 1u)) >> 16);
}
__device__ __forceinline__ float rcp_fast(float x) { return __builtin_amdgcn_rcpf(x); }
__device__ __forceinline__ float sigm(float x) { return rcp_fast(1.0f + __expf(-x)); }
__device__ __forceinline__ float tanh1(float x) {
    float e = __expf(2.0f * x);
    return 1.0f - 2.0f * rcp_fast(e + 1.0f);
}
__device__ __forceinline__ void cstore(float* p, float v) {
    __hip_atomic_store(p, v, __ATOMIC_RELAXED, __HIP_MEMORY_SCOPE_AGENT);
}
__device__ __forceinline__ float cload(const float* p) {
    return __hip_atomic_load(p, __ATOMIC_RELAXED, __HIP_MEMORY_SCOPE_AGENT);
}

#if __has_builtin(__builtin_amdgcn_fdot2)
__device__ __forceinline__ float dot2(f16x2 w, f16x2 h, float a) {
    return __builtin_amdgcn_fdot2(w, h, a, false);
}
#else
__device__ __forceinline__ float dot2(f16x2 w, f16x2 h, float a) {
    return fmaf((float)w.x, (float)h.x, fmaf((float)w.y, (float)h.y, a));
}
#endif

// per-gang barrier (8 arrivals, monotonic epochs, fence-free)
__device__ __forceinline__ void gangbar(int* cnt, int need) {
    __syncthreads();
    if (threadIdx.x == 0) {
        asm volatile("s_waitcnt vmcnt(0) lgkmcnt(0)" ::: "memory");
        __hip_atomic_fetch_add(cnt, 1, __ATOMIC_RELAXED, __HIP_MEMORY_SCOPE_AGENT);
        while (__hip_atomic_load(cnt, __ATOMIC_RELAXED, __HIP_MEMORY_SCOPE_AGENT) < need) {
            __builtin_amdgcn_s_sleep(1);
        }
        asm volatile("" ::: "memory");
    }
    __syncthreads();
}

// ---------------- fused prologue: init | w1pack(f16) | keys | encwx | zemb ----------------
__launch_bounds__(256)
__global__ void prologue_kernel(const int* __restrict__ dec, const float* __restrict__ enc,
                                const float* __restrict__ emb, const float* __restrict__ W1,
                                const float* __restrict__ W2, const float* __restrict__ b2,
                                const float* __restrict__ Wx, const float* __restrict__ b_lstm,
                                float* __restrict__ rs, int* __restrict__ bar,
                                unsigned int* __restrict__ W1h, unsigned short* __restrict__ keysT,
                                float* __restrict__ encWx, float* __restrict__ zemb) {
    int blk = blockIdx.x, tid = threadIdx.x;
    if (blk < 4) {
        int idx = blk * 256 + tid;
        rs[idx] = 0.f;
        bar[idx] = 0;
    } else if (blk < 132) {
        // W1 -> f16 pairs: W1h[dp*256+u] = (f16(W1[2dp][u]), f16(W1[2dp+1][u]))
        int id = (blk - 4) * 256 + tid;
        int dp = id >> 8, u = id & 255;
        unsigned short lo = __builtin_bit_cast(unsigned short, (_Float16)W1[(size_t)(2 * dp) * NU + u]);
        unsigned short hi = __builtin_bit_cast(unsigned short, (_Float16)W1[(size_t)(2 * dp + 1) * NU + u]);
        W1h[id] = (unsigned int)lo | ((unsigned int)hi << 16);
    } else if (blk < 260) {
        // keysT[b][u][s] = (enc @ W2 + b2)^T bf16 ; 16 rows of s per block
        int bb = (blk - 132) >> 3, sg = (blk - 132) & 7;
        int u = tid;
        float acc[16];
        float bias = b2[u];
#pragma unroll
        for (int r = 0; r < 16; r++) acc[r] = bias;
        const float4* e4 = (const float4*)(enc + ((size_t)bb * NS + sg * 16) * DE);
        const float* wp = W2 + u;
        for (int k4 = 0; k4 < DE / 4; k4++) {
            float w0 = wp[(size_t)(k4 * 4 + 0) * NU];
            float w1 = wp[(size_t)(k4 * 4 + 1) * NU];
            float w2v = wp[(size_t)(k4 * 4 + 2) * NU];
            float w3v = wp[(size_t)(k4 * 4 + 3) * NU];
#pragma unroll
            for (int r = 0; r < 16; r++) {
                float4 e = e4[(size_t)r * (DE / 4) + k4];  // wave-uniform
                acc[r] = fmaf(e.x, w0, fmaf(e.y, w1, fmaf(e.z, w2v, fmaf(e.w, w3v, acc[r]))));
            }
        }
        unsigned int ow[8];
#pragma unroll
        for (int i = 0; i < 8; i++)
            ow[i] = (unsigned int)f2bf(acc[2 * i]) | ((unsigned int)f2bf(acc[2 * i + 1]) << 16);
        uint4* dst = (uint4*)(keysT + ((size_t)bb * NU + u) * NS + sg * 16);
        dst[0] = make_uint4(ow[0], ow[1], ow[2], ow[3]);
        dst[1] = make_uint4(ow[4], ow[5], ow[6], ow[7]);
    } else if (blk < 516) {
        // encWx[(b,s)][j] = enc @ Wx[0:512]
        int rg = (blk - 260) >> 2, jq = (blk - 260) & 3;
        int j = jq * 256 + tid;
        float acc[32];
#pragma unroll
        for (int r = 0; r < 32; r++) acc[r] = 0.f;
        const float4* e4 = (const float4*)(enc + (size_t)rg * 32 * DE);
        const float* wp = Wx + j;
        for (int k4 = 0; k4 < DE / 4; k4++) {
            float w0 = wp[(size_t)(k4 * 4 + 0) * 1024];
            float w1 = wp[(size_t)(k4 * 4 + 1) * 1024];
            float w2v = wp[(size_t)(k4 * 4 + 2) * 1024];
            float w3v = wp[(size_t)(k4 * 4 + 3) * 1024];
#pragma unroll
            for (int r = 0; r < 32; r++) {
                float4 e = e4[(size_t)r * (DE / 4) + k4];  // wave-uniform
                acc[r] = fmaf(e.x, w0, fmaf(e.y, w1, fmaf(e.z, w2v, fmaf(e.w, w3v, acc[r]))));
            }
        }
#pragma unroll
        for (int r = 0; r < 32; r++) encWx[(size_t)(rg * 32 + r) * 1024 + j] = acc[r];
    } else {
        // zemb[(b,t)][j] = emb[tok] @ Wx[512:768] + b_lstm
        int rg = (blk - 516) >> 2, jq = (blk - 516) & 3;
        int j = jq * 256 + tid;
        int tokr[32];
#pragma unroll
        for (int r = 0; r < 32; r++) {
            int row = rg * 32 + r;
            int tok = dec[(row >> 6) * NT + (row & 63)];
            tokr[r] = (tok < 0) ? 0 : (tok >= NV ? NV - 1 : tok);
        }
        float acc[32];
        float bias = b_lstm[j];
#pragma unroll
        for (int r = 0; r < 32; r++) acc[r] = bias;
        const float* wp = Wx + (size_t)512 * 1024 + j;
        for (int k4 = 0; k4 < NU / 4; k4++) {
            float w0 = wp[(size_t)(k4 * 4 + 0) * 1024];
            float w1 = wp[(size_t)(k4 * 4 + 1) * 1024];
            float w2v = wp[(size_t)(k4 * 4 + 2) * 1024];
            float w3v = wp[(size_t)(k4 * 4 + 3) * 1024];
#pragma unroll
            for (int r = 0; r < 32; r++) {
                float4 e = ((const float4*)(emb + (size_t)tokr[r] * NU))[k4];  // uniform
                acc[r] = fmaf(e.x, w0, fmaf(e.y, w1, fmaf(e.z, w2v, fmaf(e.w, w3v, acc[r]))));
            }
        }
#pragma unroll
        for (int r = 0; r < 32; r++) zemb[(size_t)(rg * 32 + r) * 1024 + j] = acc[r];
    }
}

// ---------------- Wd -> fragment-tiled bf16 (after recur) ----------------
__launch_bounds__(256)
__global__ void wdtile_kernel(const float* __restrict__ Wd, unsigned short* __restrict__ wdT) {
    int id = blockIdx.x * 256 + threadIdx.x;
    int l = id & 63, c16 = (id >> 6) & 7, ks = (id >> 9) & 7, p = id >> 12;
    int v = p * 128 + c16 * 16 + (l & 15);
    int k0 = ks * 32 + (l >> 4) * 8;
    unsigned int wout[4];
#pragma unroll
    for (int jj = 0; jj < 4; jj++) {
        unsigned int lo = f2bf(Wd[(size_t)(k0 + 2 * jj) * NV + v]);
        unsigned int hi = f2bf(Wd[(size_t)(k0 + 2 * jj + 1) * NV + v]);
        wout[jj] = lo | (hi << 16);
    }
    *(uint4*)(wdT + (size_t)id * 8) = make_uint4(wout[0], wout[1], wout[2], wout[3]);
}

// ---------------- persistent recurrence: 16 gangs x 8 blocks x 512 thr ----------------
// 86 KB LDS forces 1 block/CU (no gang-member SIMD contention).
__launch_bounds__(512, 2)
__global__ void recur_kernel(const float* __restrict__ b1, const float* __restrict__ Va,
                             const float* __restrict__ bV, const float* __restrict__ Wh,
                             const float* __restrict__ h0, const float* __restrict__ c0,
                             const unsigned short* __restrict__ keysT,
                             const unsigned int* __restrict__ W1h,
                             const float* __restrict__ encWx, const float* __restrict__ zemb,
                             float* __restrict__ zfull, unsigned short* __restrict__ Hb,
                             int* __restrict__ bar) {
    __shared__ float smem[21504];  // 86 KB: pad to exclude a 2nd block on the CU
    float* hl = smem;               // 256
    _Float16* hf = (_Float16*)(smem + 256);  // 256 f16 (128 fl)
    float* qv = smem + 384;         // 256
    float* qred = smem + 640;       // 512
    float* scp = smem + 1152;       // 512
    float* red = smem + 1664;       // 136
    float* xcat = smem + 1800;      // 384
    float* zred = smem + 2184;      // 512

    int tid = threadIdx.x;
    int b = blockIdx.x & 15;        // gang = batch
    int r = blockIdx.x >> 4;        // 0..7 -> j-slice r*128
    int* cnt = bar + b * 64;
    int jl = tid & 127, kg = tid >> 7;  // j-lane, k-group (4 x 96)
    int j = r * 128 + jl;

    float c_reg = (tid < NU) ? c0[b * NU + tid] : 0.f;
    float bV0 = bV[0];

    // pin 96 z-weights per thread (fp32): k<128 attn part (encWx), else h part (Wh)
    float wreg[96];
    {
        const float* ew = encWx + (size_t)b * 128 * 1024 + j;
        const float* wh = Wh + j;
#pragma unroll
        for (int i = 0; i < 96; i++) {
            int k = kg * 96 + i;
            wreg[i] = (k < 128) ? ew[(size_t)k * 1024] : wh[(size_t)(k - 128) * 1024];
        }
    }

    for (int it = 0; it <= NT; ++it) {
        // prefetch zemb row for this step (used in z-phase, ~4 phases later)
        float zpre = 0.f;
        if (it < NT && tid < 128)
            zpre = zemb[((size_t)b * NT + it) * 1024 + r * 128 + tid];

        // ---- gates (tid<256) ----
        if (tid < NU) {
            float hn;
            if (it > 0) {
                const float* zb = zfull + (size_t)(((it - 1) & 1) * NB + b) * 1024;
                float zi = cload(zb + tid);
                float zf = cload(zb + 256 + tid);
                float zg = cload(zb + 512 + tid);
                float zo = cload(zb + 768 + tid);
                float cn = sigm(zf) * c_reg + sigm(zi) * tanh1(zg);
                c_reg = cn;
                hn = sigm(zo) * tanh1(cn);
                if (r == 0) {
                    int rr = (it - 1) * NB + b;
                    int mp = rr >> 7, lr = rr & 127;
                    int chunk = ((tid >> 5) * 8 + (lr >> 4)) * 64 + ((tid >> 3) & 3) * 16 + (lr & 15);
                    Hb[(size_t)mp * 32768 + chunk * 8 + (tid & 7)] = f2bf(hn);
                }
            } else {
                hn = h0[b * NU + tid];
            }
            hl[tid] = hn;
            hf[tid] = (_Float16)hn;
        }
        __syncthreads();
        if (it == NT) break;

        // ---- q = h @ W1(f16 dot2) : 512 thr = 256 u x 2 d-halves ----
        {
            int u0 = tid & 255, dh = tid >> 8;
            const unsigned int* wp = W1h + dh * 64 * 256 + u0;
            const f16x2* hp = (const f16x2*)hf + dh * 64;
            float a = 0.f;
#pragma unroll 8
            for (int dp = 0; dp < 64; dp++) {
                f16x2 wv = __builtin_bit_cast(f16x2, wp[(size_t)dp * 256]);
                a = dot2(wv, hp[dp], a);
            }
            qred[dh * 256 + u0] = a;
        }
        __syncthreads();
        if (tid < NU) qv[tid] = qred[tid] + qred[256 + tid] + b1[tid];
        __syncthreads();

        // ---- scores: 512 thr = 128 s x 4 u-groups(64) ----
        {
            int s = tid & 127, ug = tid >> 7;
            const unsigned short* kp = keysT + ((size_t)b * NU + ug * 64) * NS + s;
            float sc = 0.f;
#pragma unroll 4
            for (int uu = 0; uu < 64; uu++)
                sc = fmaf(tanh1(qv[ug * 64 + uu] + bf2f(kp[(size_t)uu * NS])),
                          Va[ug * 64 + uu], sc);
            scp[ug * 128 + s] = sc;
        }
        __syncthreads();
        // ---- softmax without max-pass (scores bounded: |s| <= sum|Va| ~ 13) ----
        float p = 0.f;
        if (tid < 128) {
            float sfull = scp[tid] + scp[128 + tid] + scp[256 + tid] + scp[384 + tid] + bV0;
            p = __expf(sfull);
            red[tid] = p;
        }
        __syncthreads();
        if (tid < 64) {
            float v = red[tid] + red[tid + 64];
#pragma unroll
            for (int off = 32; off >= 1; off >>= 1) v += __shfl_xor(v, off, 64);
            if (tid == 0) red[128] = v;
        }
        __syncthreads();
        float tot = red[128];
        // xcat = [attn(128) | h(256)]
        if (tid < 128) xcat[tid] = p * rcp_fast(tot);
        else if (tid < 384) xcat[tid] = hl[tid - 128];
        __syncthreads();

        // ---- z slice: 96 register-weight FMAs ----
        float zacc = 0.f;
        const float* xk = xcat + kg * 96;
#pragma unroll
        for (int i = 0; i < 96; i++) zacc = fmaf(wreg[i], xk[i], zacc);
        zred[kg * 128 + jl] = zacc;
        __syncthreads();
        if (tid < 128) {
            float z = zred[tid] + zred[128 + tid] + zred[256 + tid] + zred[384 + tid] + zpre;
            cstore(&zfull[(size_t)((it & 1) * NB + b) * 1024 + r * 128 + tid], z);
        }
        gangbar(cnt, (it + 1) * 8);
    }
}

// ---------------- two-pass vocab GEMM: PASS 0 = exp+rowsum, PASS 1 = write ----------------
template <int PASS>
__launch_bounds__(256)
__global__ void gemm_kernel(const unsigned short* __restrict__ Hb,
                            const unsigned short* __restrict__ wdT,
                            const float* __restrict__ bd, float* __restrict__ out,
                            float* __restrict__ rs) {
    int w = (blockIdx.x & 7) * 250 + (blockIdx.x >> 3);
    int np = w >> 3, mp = w & 7;
    int wave = threadIdx.x >> 6, l = threadIdx.x & 63;
    int wm = wave >> 1, wn = wave & 1;
    const bf16x8* A = (const bf16x8*)Hb + (size_t)mp * 4096;
    const bf16x8* B = (const bf16x8*)wdT + (size_t)np * 4096;
    f32x4 acc[4][4];
#pragma unroll
    for (int mf = 0; mf < 4; mf++)
#pragma unroll
        for (int nf = 0; nf < 4; nf++) acc[mf][nf] = (f32x4){0.f, 0.f, 0.f, 0.f};
#pragma unroll
    for (int ks = 0; ks < 8; ks++) {
        bf16x8 av[4], bv[4];
#pragma unroll
        for (int mf = 0; mf < 4; mf++) av[mf] = A[(ks * 8 + wm * 4 + mf) * 64 + l];
#pragma unroll
        for (int nf = 0; nf < 4; nf++) bv[nf] = B[(ks * 8 + wn * 4 + nf) * 64 + l];
#pragma unroll
        for (int mf = 0; mf < 4; mf++)
#pragma unroll
            for (int nf = 0; nf < 4; nf++)
                acc[mf][nf] =
                    __builtin_amdgcn_mfma_f32_16x16x32_bf16(av[mf], bv[nf], acc[mf][nf], 0, 0, 0);
    }
    int colg = np * 128 + wn * 64;
    int rowg = mp * 128 + wm * 64;
#pragma unroll
    for (int mf = 0; mf < 4; mf++) {
        float rloc[4] = {0.f, 0.f, 0.f, 0.f};
        float rinv[4];
        if constexpr (PASS == 1) {
#pragma unroll
            for (int reg = 0; reg < 4; reg++)
                rinv[reg] = 1.0f / rs[rowg + mf * 16 + (l >> 4) * 4 + reg];
        }
#pragma unroll
        for (int nf = 0; nf < 4; nf++) {
            int col = colg + nf * 16 + (l & 15);
            float bdv = bd[col];
#pragma unroll
            for (int reg = 0; reg < 4; reg++) {
                float p = __expf(acc[mf][nf][reg] + bdv);
                if constexpr (PASS == 0) {
                    rloc[reg] += p;
                } else {
                    int rr = rowg + mf * 16 + (l >> 4) * 4 + reg;  // rr = t*16 + b
                    out[(size_t)((rr & 15) * NT + (rr >> 4)) * NV + col] = p * rinv[reg];
                }
            }
        }
        if constexpr (PASS == 0) {
#pragma unroll
            for (int reg = 0; reg < 4; reg++) {
                float v = rloc[reg];
                v += __shfl_xor(v, 1);
                v += __shfl_xor(v, 2);
                v += __shfl_xor(v, 4);
                v += __shfl_xor(v, 8);
                if ((l & 15) == 0) atomicAdd(&rs[rowg + mf * 16 + (l >> 4) * 4 + reg], v);
            }
        }
    }
}

extern "C" void kernel_launch(void* const* d_in, const int* in_sizes, int n_in,
                              void* d_out, int out_size, void* d_ws, size_t ws_size,
                              hipStream_t stream) {
    const int* dec = (const int*)d_in[0];
    const float* enc = (const float*)d_in[1];
    const float* h0 = (const float*)d_in[2];
    const float* c0 = (const float*)d_in[3];
    const float* emb = (const float*)d_in[4];
    const float* W1 = (const float*)d_in[5];
    const float* b1 = (const float*)d_in[6];
    const float* W2 = (const float*)d_in[7];
    const float* b2 = (const float*)d_in[8];
    const float* Va = (const float*)d_in[9];
    const float* bV = (const float*)d_in[10];
    const float* Wx = (const float*)d_in[11];
    const float* Wh = (const float*)d_in[12];
    const float* b_lstm = (const float*)d_in[13];
    const float* Wd = (const float*)d_in[14];
    const float* bd = (const float*)d_in[15];
    float* out = (float*)d_out;
    float* ws = (float*)d_ws;

    unsigned short* keysT = (unsigned short*)(ws + OFF_KEYS);
    float* zfull = ws + OFF_ZF;
    float* ws_rs = ws + OFF_RS;
    int* bar = (int*)(ws + OFF_BAR);
    unsigned short* Hb = (unsigned short*)(ws + OFF_HBUF);
    unsigned int* W1h = (unsigned int*)(ws + OFF_W1P);
    float* encWx = ws + OFF_ENCWX;
    float* zemb = ws + OFF_ZEMB;
    unsigned short* wdT = (unsigned short*)(ws + OFF_WDT);

    prologue_kernel<<<644, 256, 0, stream>>>(dec, enc, emb, W1, W2, b2, Wx, b_lstm,
                                             ws_rs, bar, W1h, keysT, encWx, zemb);
    recur_kernel<<<128, 512, 0, stream>>>(b1, Va, bV, Wh, h0, c0, keysT, W1h, encWx, zemb,
                                          zfull, Hb, bar);
    wdtile_kernel<<<4000, 256, 0, stream>>>(Wd, wdT);  // overwrites W1h/encWx/zemb
    gemm_kernel<0><<<2000, 256, 0, stream>>>(Hb, wdT, bd, out, ws_rs);
    gemm_kernel<1><<<2000, 256, 0, stream>>>(Hb, wdT, bd, out, ws_rs);
}

// Round 11
// 748.026 us; speedup vs baseline: 3.6824x; 1.0090x over previous
//
#include <hip/hip_runtime.h>

// Decoder, B=16, T=64, S=128, D_ENC=512, U=256, V=32000.
// Round 11: flag-based one-sided exchange. 16 gangs (1/batch) x 8 blocks x
// 512 thr, 1 block/CU (LDS pad). Block r owns z-cols {g*256+r*32+i} -> gates
// are LOCAL; only h (32 fl/block) crosses L3, parity-dbuffed, guarded by
// per-producer flags (store h -> vmcnt(0) -> store flag; consumers wave-poll).
// Softmax normalization deferred into z (z_attn = (sum p*w) * rcp(tot)).
// Epilogue: wdtile + two-pass MFMA vocab GEMM (exp+rowsum, then write).

#define NB 16
#define NT 64
#define NS 128
#define DE 512
#define NU 256
#define NV 32000

// ws layout (floats); total 18.10 MB (proven available)
static const size_t OFF_KEYS  = 0;          // keysT bf16 [16][256][128] -> 262144
static const size_t OFF_HX    = 262144;     // hx dbuf [2][16][256] -> 8192 (in old ZF region)
static const size_t OFF_RS    = 294912;     // rowsums [1024]
static const size_t OFF_BAR   = 295936;     // flags[16][64] ints (1024 ints)
static const size_t OFF_HBUF  = 296960;     // Hb fragment-tiled bf16 -> 131072
static const size_t OFF_W1P   = 428032;     // W1 f16-packed [128][256] uint -> 32768
static const size_t OFF_ENCWX = 460800;     // [16*128][1024] fp32 -> 2097152
static const size_t OFF_ZEMB  = 2557952;    // [16*64][1024] fp32 -> 1048576
static const size_t OFF_WDT   = 428032;     // wdT bf16 tiled (4096000 fl), after recur

typedef __attribute__((ext_vector_type(8))) short bf16x8;
typedef __attribute__((ext_vector_type(4))) float f32x4;
typedef __attribute__((ext_vector_type(2))) _Float16 f16x2;

__device__ __forceinline__ float bf2f(unsigned int us) { return __uint_as_float(us << 16); }
__device__ __forceinline__ unsigned short f2bf(float f) {
    unsigned int u = __float_as_uint(f);
    return (unsigned short)((u + 0x7fffu + ((u >> 16) & 1u)) >> 16);
}
__device__ __forceinline__ float rcp_fast(float x) { return __builtin_amdgcn_rcpf(x); }
__device__ __forceinline__ float sigm(float x) { return rcp_fast(1.0f + __expf(-x)); }
__device__ __forceinline__ float tanh1(float x) {
    float e = __expf(2.0f * x);
    return 1.0f - 2.0f * rcp_fast(e + 1.0f);
}
__device__ __forceinline__ void cstore(float* p, float v) {
    __hip_atomic_store(p, v, __ATOMIC_RELAXED, __HIP_MEMORY_SCOPE_AGENT);
}
__device__ __forceinline__ float cload(const float* p) {
    return __hip_atomic_load(p, __ATOMIC_RELAXED, __HIP_MEMORY_SCOPE_AGENT);
}
__device__ __forceinline__ void cstore_i(int* p, int v) {
    __hip_atomic_store(p, v, __ATOMIC_RELAXED, __HIP_MEMORY_SCOPE_AGENT);
}
__device__ __forceinline__ int cload_i(const int* p) {
    return __hip_atomic_load(p, __ATOMIC_RELAXED, __HIP_MEMORY_SCOPE_AGENT);
}

#if __has_builtin(__builtin_amdgcn_fdot2)
__device__ __forceinline__ float dot2(f16x2 w, f16x2 h, float a) {
    return __builtin_amdgcn_fdot2(w, h, a, false);
}
#else
__device__ __forceinline__ float dot2(f16x2 w, f16x2 h, float a) {
    return fmaf((float)w.x, (float)h.x, fmaf((float)w.y, (float)h.y, a));
}
#endif

// ---------------- fused prologue: init | w1pack(f16) | keys | encwx | zemb ----------------
__launch_bounds__(256)
__global__ void prologue_kernel(const int* __restrict__ dec, const float* __restrict__ enc,
                                const float* __restrict__ emb, const float* __restrict__ W1,
                                const float* __restrict__ W2, const float* __restrict__ b2,
                                const float* __restrict__ Wx, const float* __restrict__ b_lstm,
                                float* __restrict__ rs, int* __restrict__ bar,
                                unsigned int* __restrict__ W1h, unsigned short* __restrict__ keysT,
                                float* __restrict__ encWx, float* __restrict__ zemb) {
    int blk = blockIdx.x, tid = threadIdx.x;
    if (blk < 4) {
        int idx = blk * 256 + tid;
        rs[idx] = 0.f;
        bar[idx] = 0;
    } else if (blk < 132) {
        int id = (blk - 4) * 256 + tid;
        int dp = id >> 8, u = id & 255;
        unsigned short lo = __builtin_bit_cast(unsigned short, (_Float16)W1[(size_t)(2 * dp) * NU + u]);
        unsigned short hi = __builtin_bit_cast(unsigned short, (_Float16)W1[(size_t)(2 * dp + 1) * NU + u]);
        W1h[id] = (unsigned int)lo | ((unsigned int)hi << 16);
    } else if (blk < 260) {
        int bb = (blk - 132) >> 3, sg = (blk - 132) & 7;
        int u = tid;
        float acc[16];
        float bias = b2[u];
#pragma unroll
        for (int r = 0; r < 16; r++) acc[r] = bias;
        const float4* e4 = (const float4*)(enc + ((size_t)bb * NS + sg * 16) * DE);
        const float* wp = W2 + u;
        for (int k4 = 0; k4 < DE / 4; k4++) {
            float w0 = wp[(size_t)(k4 * 4 + 0) * NU];
            float w1 = wp[(size_t)(k4 * 4 + 1) * NU];
            float w2v = wp[(size_t)(k4 * 4 + 2) * NU];
            float w3v = wp[(size_t)(k4 * 4 + 3) * NU];
#pragma unroll
            for (int r = 0; r < 16; r++) {
                float4 e = e4[(size_t)r * (DE / 4) + k4];  // wave-uniform
                acc[r] = fmaf(e.x, w0, fmaf(e.y, w1, fmaf(e.z, w2v, fmaf(e.w, w3v, acc[r]))));
            }
        }
        unsigned int ow[8];
#pragma unroll
        for (int i = 0; i < 8; i++)
            ow[i] = (unsigned int)f2bf(acc[2 * i]) | ((unsigned int)f2bf(acc[2 * i + 1]) << 16);
        uint4* dst = (uint4*)(keysT + ((size_t)bb * NU + u) * NS + sg * 16);
        dst[0] = make_uint4(ow[0], ow[1], ow[2], ow[3]);
        dst[1] = make_uint4(ow[4], ow[5], ow[6], ow[7]);
    } else if (blk < 516) {
        int rg = (blk - 260) >> 2, jq = (blk - 260) & 3;
        int j = jq * 256 + tid;
        float acc[32];
#pragma unroll
        for (int r = 0; r < 32; r++) acc[r] = 0.f;
        const float4* e4 = (const float4*)(enc + (size_t)rg * 32 * DE);
        const float* wp = Wx + j;
        for (int k4 = 0; k4 < DE / 4; k4++) {
            float w0 = wp[(size_t)(k4 * 4 + 0) * 1024];
            float w1 = wp[(size_t)(k4 * 4 + 1) * 1024];
            float w2v = wp[(size_t)(k4 * 4 + 2) * 1024];
            float w3v = wp[(size_t)(k4 * 4 + 3) * 1024];
#pragma unroll
            for (int r = 0; r < 32; r++) {
                float4 e = e4[(size_t)r * (DE / 4) + k4];  // wave-uniform
                acc[r] = fmaf(e.x, w0, fmaf(e.y, w1, fmaf(e.z, w2v, fmaf(e.w, w3v, acc[r]))));
            }
        }
#pragma unroll
        for (int r = 0; r < 32; r++) encWx[(size_t)(rg * 32 + r) * 1024 + j] = acc[r];
    } else {
        int rg = (blk - 516) >> 2, jq = (blk - 516) & 3;
        int j = jq * 256 + tid;
        int tokr[32];
#pragma unroll
        for (int r = 0; r < 32; r++) {
            int row = rg * 32 + r;
            int tok = dec[(row >> 6) * NT + (row & 63)];
            tokr[r] = (tok < 0) ? 0 : (tok >= NV ? NV - 1 : tok);
        }
        float acc[32];
        float bias = b_lstm[j];
#pragma unroll
        for (int r = 0; r < 32; r++) acc[r] = bias;
        const float* wp = Wx + (size_t)512 * 1024 + j;
        for (int k4 = 0; k4 < NU / 4; k4++) {
            float w0 = wp[(size_t)(k4 * 4 + 0) * 1024];
            float w1 = wp[(size_t)(k4 * 4 + 1) * 1024];
            float w2v = wp[(size_t)(k4 * 4 + 2) * 1024];
            float w3v = wp[(size_t)(k4 * 4 + 3) * 1024];
#pragma unroll
            for (int r = 0; r < 32; r++) {
                float4 e = ((const float4*)(emb + (size_t)tokr[r] * NU))[k4];  // uniform
                acc[r] = fmaf(e.x, w0, fmaf(e.y, w1, fmaf(e.z, w2v, fmaf(e.w, w3v, acc[r]))));
            }
        }
#pragma unroll
        for (int r = 0; r < 32; r++) zemb[(size_t)(rg * 32 + r) * 1024 + j] = acc[r];
    }
}

// ---------------- Wd -> fragment-tiled bf16 (after recur) ----------------
__launch_bounds__(256)
__global__ void wdtile_kernel(const float* __restrict__ Wd, unsigned short* __restrict__ wdT) {
    int id = blockIdx.x * 256 + threadIdx.x;
    int l = id & 63, c16 = (id >> 6) & 7, ks = (id >> 9) & 7, p = id >> 12;
    int v = p * 128 + c16 * 16 + (l & 15);
    int k0 = ks * 32 + (l >> 4) * 8;
    unsigned int wout[4];
#pragma unroll
    for (int jj = 0; jj < 4; jj++) {
        unsigned int lo = f2bf(Wd[(size_t)(k0 + 2 * jj) * NV + v]);
        unsigned int hi = f2bf(Wd[(size_t)(k0 + 2 * jj + 1) * NV + v]);
        wout[jj] = lo | (hi << 16);
    }
    *(uint4*)(wdT + (size_t)id * 8) = make_uint4(wout[0], wout[1], wout[2], wout[3]);
}

// ---------------- persistent recurrence: flags, local gates ----------------
__launch_bounds__(512, 2)
__global__ void recur_kernel(const float* __restrict__ b1, const float* __restrict__ Va,
                             const float* __restrict__ bV, const float* __restrict__ Wh,
                             const float* __restrict__ h0, const float* __restrict__ c0,
                             const unsigned short* __restrict__ keysT,
                             const unsigned int* __restrict__ W1h,
                             const float* __restrict__ encWx, const float* __restrict__ zemb,
                             float* __restrict__ hx, unsigned short* __restrict__ Hb,
                             int* __restrict__ flags) {
    __shared__ float smem[21504];  // 86 KB pad: 1 block/CU
    float* hl = smem;                        // 256
    _Float16* hf = (_Float16*)(smem + 256);  // 256 f16
    float* qred = smem + 384;                // 512
    float* qv = smem + 896;                  // 256
    float* scp = smem + 1152;                // 512
    float* red = smem + 1664;                // 136
    float* attnp = smem + 1800;              // 128 (raw exp p)
    float* zred = smem + 1928;               // 512

    int tid = threadIdx.x;
    int b = blockIdx.x & 15;        // gang = batch (gang XCD-local by round-robin)
    int r = blockIdx.x >> 4;        // 0..7
    int kg = tid >> 7, jl = tid & 127;
    int g = jl >> 5, i32 = jl & 31;
    int j = g * 256 + r * 32 + i32;  // scattered j: block owns all 4 gates for u in [r*32, r*32+32)
    int* flagg = flags + b * 64;     // this gang's 8 flags (first 32B)

    float bV0 = bV[0];
    float c_reg = (tid < 32) ? c0[b * NU + r * 32 + tid] : 0.f;

    // pin 96 z-weights/thread: k = kg*96+kk; k<128 -> attn (encWx col j), else h (Wh col j)
    float wreg[96];
    {
        const float* ew = encWx + (size_t)b * 128 * 1024 + j;
        const float* wh = Wh + j;
#pragma unroll
        for (int kk = 0; kk < 96; kk++) {
            int k = kg * 96 + kk;
            wreg[kk] = (k < 128) ? ew[(size_t)k * 1024] : wh[(size_t)(k - 128) * 1024];
        }
    }

    for (int it = 0; it < NT; ++it) {
        // zemb prefetch for the gates (4 values, tid<32)
        float zpre4[4];
        if (tid < 32) {
#pragma unroll
            for (int gg = 0; gg < 4; gg++)
                zpre4[gg] = zemb[((size_t)b * NT + it) * 1024 + gg * 256 + r * 32 + tid];
        }
        // ---- acquire h_t: waves 0-3 poll flags then coherent-load ----
        if (tid < NU) {
            float hv;
            if (it == 0) {
                hv = h0[b * NU + tid];
            } else {
                int lane = tid & 63;
                while (true) {
                    int f = cload_i(flagg + (lane & 7));
                    if (__all(f >= it)) break;
                    __builtin_amdgcn_s_sleep(2);
                }
                hv = cload(hx + (size_t)(it & 1) * 4096 + b * NU + tid);
            }
            hl[tid] = hv;
            hf[tid] = (_Float16)hv;
        }
        __syncthreads();  // S1

        // ---- q = h @ W1(f16 dot2): 512 thr = 256 u x 2 d-halves ----
        {
            int u0 = tid & 255, dh = tid >> 8;
            const unsigned int* wp = W1h + dh * 64 * 256 + u0;
            const f16x2* hp = (const f16x2*)hf + dh * 64;
            float a = 0.f;
#pragma unroll 8
            for (int dp = 0; dp < 64; dp++) {
                f16x2 wv = __builtin_bit_cast(f16x2, wp[(size_t)dp * 256]);
                a = dot2(wv, hp[dp], a);
            }
            qred[dh * 256 + u0] = a;
        }
        __syncthreads();  // S2
        if (tid < NU) qv[tid] = qred[tid] + qred[256 + tid] + b1[tid];
        __syncthreads();  // S3

        // ---- scores: 512 thr = 128 s x 4 u-groups(64) ----
        {
            int s = tid & 127, ug = tid >> 7;
            const unsigned short* kp = keysT + ((size_t)b * NU + ug * 64) * NS + s;
            float sc = 0.f;
#pragma unroll 4
            for (int uu = 0; uu < 64; uu++)
                sc = fmaf(tanh1(qv[ug * 64 + uu] + bf2f(kp[(size_t)uu * NS])),
                          Va[ug * 64 + uu], sc);
            scp[ug * 128 + s] = sc;
        }
        __syncthreads();  // S4
        // ---- exp (no max-pass; scores bounded by sum|Va|) ----
        if (tid < 128) {
            float sfull = scp[tid] + scp[128 + tid] + scp[256 + tid] + scp[384 + tid] + bV0;
            float p = __expf(sfull);
            attnp[tid] = p;
            red[tid] = p;
        }
        __syncthreads();  // S5
        // wave 0: tot reduce (runs while other waves begin z-FMA)
        if (tid < 64) {
            float v = red[tid] + red[tid + 64];
#pragma unroll
            for (int off = 32; off >= 1; off >>= 1) v += __shfl_xor(v, off, 64);
            if (tid == 0) red[128] = v;
        }
        // ---- z slice: 96 register-weight FMAs, attn part kept unnormalized ----
        float aA = 0.f, aH = 0.f;
        if (kg == 0) {
#pragma unroll
            for (int kk = 0; kk < 96; kk++) aA = fmaf(wreg[kk], attnp[kk], aA);
        } else if (kg == 1) {
#pragma unroll
            for (int kk = 0; kk < 32; kk++) aA = fmaf(wreg[kk], attnp[96 + kk], aA);
#pragma unroll
            for (int kk = 32; kk < 96; kk++) aH = fmaf(wreg[kk], hl[kk - 32], aH);
        } else {
            int base = kg * 96 - 128;
#pragma unroll
            for (int kk = 0; kk < 96; kk++) aH = fmaf(wreg[kk], hl[base + kk], aH);
        }
        __syncthreads();  // S6 (red[128] ready)
        float rinv = rcp_fast(red[128]);
        zred[kg * 128 + jl] = aA * rinv + aH;
        __syncthreads();  // S7

        // ---- local gates (tid<32): all 4 gate values for u = r*32+tid are in zred ----
        if (tid < 32) {
            float z4[4];
#pragma unroll
            for (int gg = 0; gg < 4; gg++) {
                int jj = gg * 32 + tid;
                z4[gg] = zred[jj] + zred[128 + jj] + zred[256 + jj] + zred[384 + jj] + zpre4[gg];
            }
            float cn = sigm(z4[1]) * c_reg + sigm(z4[0]) * tanh1(z4[2]);
            c_reg = cn;
            float hn = sigm(z4[3]) * tanh1(cn);
            int u = r * 32 + tid;
            // Hb fragment write (output row = it)
            int rr = it * NB + b;
            int mp = rr >> 7, lr = rr & 127;
            int chunk = ((u >> 5) * 8 + (lr >> 4)) * 64 + ((u >> 3) & 3) * 16 + (lr & 15);
            Hb[(size_t)mp * 32768 + chunk * 8 + (u & 7)] = f2bf(hn);
            // h exchange (parity dbuf)
            cstore(hx + (size_t)((it + 1) & 1) * 4096 + b * NU + u, hn);
        }
        if (tid < 64) asm volatile("s_waitcnt vmcnt(0)" ::: "memory");  // drain wave-0 stores
        if (tid == 0) cstore_i(flagg + r, it + 1);
        // no block-wide sync: next-step poll (own flag) provides the release ordering
    }
}

// ---------------- two-pass vocab GEMM: PASS 0 = exp+rowsum, PASS 1 = write ----------------
template <int PASS>
__launch_bounds__(256)
__global__ void gemm_kernel(const unsigned short* __restrict__ Hb,
                            const unsigned short* __restrict__ wdT,
                            const float* __restrict__ bd, float* __restrict__ out,
                            float* __restrict__ rs) {
    int w = (blockIdx.x & 7) * 250 + (blockIdx.x >> 3);
    int np = w >> 3, mp = w & 7;
    int wave = threadIdx.x >> 6, l = threadIdx.x & 63;
    int wm = wave >> 1, wn = wave & 1;
    const bf16x8* A = (const bf16x8*)Hb + (size_t)mp * 4096;
    const bf16x8* B = (const bf16x8*)wdT + (size_t)np * 4096;
    f32x4 acc[4][4];
#pragma unroll
    for (int mf = 0; mf < 4; mf++)
#pragma unroll
        for (int nf = 0; nf < 4; nf++) acc[mf][nf] = (f32x4){0.f, 0.f, 0.f, 0.f};
#pragma unroll
    for (int ks = 0; ks < 8; ks++) {
        bf16x8 av[4], bv[4];
#pragma unroll
        for (int mf = 0; mf < 4; mf++) av[mf] = A[(ks * 8 + wm * 4 + mf) * 64 + l];
#pragma unroll
        for (int nf = 0; nf < 4; nf++) bv[nf] = B[(ks * 8 + wn * 4 + nf) * 64 + l];
#pragma unroll
        for (int mf = 0; mf < 4; mf++)
#pragma unroll
            for (int nf = 0; nf < 4; nf++)
                acc[mf][nf] =
                    __builtin_amdgcn_mfma_f32_16x16x32_bf16(av[mf], bv[nf], acc[mf][nf], 0, 0, 0);
    }
    int colg = np * 128 + wn * 64;
    int rowg = mp * 128 + wm * 64;
#pragma unroll
    for (int mf = 0; mf < 4; mf++) {
        float rloc[4] = {0.f, 0.f, 0.f, 0.f};
        float rinv[4];
        if constexpr (PASS == 1) {
#pragma unroll
            for (int reg = 0; reg < 4; reg++)
                rinv[reg] = 1.0f / rs[rowg + mf * 16 + (l >> 4) * 4 + reg];
        }
#pragma unroll
        for (int nf = 0; nf < 4; nf++) {
            int col = colg + nf * 16 + (l & 15);
            float bdv = bd[col];
#pragma unroll
            for (int reg = 0; reg < 4; reg++) {
                float p = __expf(acc[mf][nf][reg] + bdv);
                if constexpr (PASS == 0) {
                    rloc[reg] += p;
                } else {
                    int rr = rowg + mf * 16 + (l >> 4) * 4 + reg;  // rr = t*16 + b
                    out[(size_t)((rr & 15) * NT + (rr >> 4)) * NV + col] = p * rinv[reg];
                }
            }
        }
        if constexpr (PASS == 0) {
#pragma unroll
            for (int reg = 0; reg < 4; reg++) {
                float v = rloc[reg];
                v += __shfl_xor(v, 1);
                v += __shfl_xor(v, 2);
                v += __shfl_xor(v, 4);
                v += __shfl_xor(v, 8);
                if ((l & 15) == 0) atomicAdd(&rs[rowg + mf * 16 + (l >> 4) * 4 + reg], v);
            }
        }
    }
}

extern "C" void kernel_launch(void* const* d_in, const int* in_sizes, int n_in,
                              void* d_out, int out_size, void* d_ws, size_t ws_size,
                              hipStream_t stream) {
    const int* dec = (const int*)d_in[0];
    const float* enc = (const float*)d_in[1];
    const float* h0 = (const float*)d_in[2];
    const float* c0 = (const float*)d_in[3];
    const float* emb = (const float*)d_in[4];
    const float* W1 = (const float*)d_in[5];
    const float* b1 = (const float*)d_in[6];
    const float* W2 = (const float*)d_in[7];
    const float* b2 = (const float*)d_in[8];
    const float* Va = (const float*)d_in[9];
    const float* bV = (const float*)d_in[10];
    const float* Wx = (const float*)d_in[11];
    const float* Wh = (const float*)d_in[12];
    const float* b_lstm = (const float*)d_in[13];
    const float* Wd = (const float*)d_in[14];
    const float* bd = (const float*)d_in[15];
    float* out = (float*)d_out;
    float* ws = (float*)d_ws;

    unsigned short* keysT = (unsigned short*)(ws + OFF_KEYS);
    float* hx = ws + OFF_HX;
    float* ws_rs = ws + OFF_RS;
    int* bar = (int*)(ws + OFF_BAR);
    unsigned short* Hb = (unsigned short*)(ws + OFF_HBUF);
    unsigned int* W1h = (unsigned int*)(ws + OFF_W1P);
    float* encWx = ws + OFF_ENCWX;
    float* zemb = ws + OFF_ZEMB;
    unsigned short* wdT = (unsigned short*)(ws + OFF_WDT);

    prologue_kernel<<<644, 256, 0, stream>>>(dec, enc, emb, W1, W2, b2, Wx, b_lstm,
                                             ws_rs, bar, W1h, keysT, encWx, zemb);
    recur_kernel<<<128, 512, 0, stream>>>(b1, Va, bV, Wh, h0, c0, keysT, W1h, encWx, zemb,
                                          hx, Hb, bar);
    wdtile_kernel<<<4000, 256, 0, stream>>>(Wd, wdT);  // overwrites W1h/encWx/zemb
    gemm_kernel<0><<<2000, 256, 0, stream>>>(Hb, wdT, bd, out, ws_rs);
    gemm_kernel<1><<<2000, 256, 0, stream>>>(Hb, wdT, bd, out, ws_rs);
}

// Round 12
// 641.207 us; speedup vs baseline: 4.2959x; 1.1666x over previous
//
#include <hip/hip_runtime.h>

// Decoder, B=16, T=64, S=128, D_ENC=512, U=256, V=32000.
// Round 12: split the replicated scores (the trans-pipe bottleneck) across the
// gang: block r computes s in [16r,16r+16) only, exchanges raw p=exp(score)
// via flag-protocol (parity dbuf). q stays replicated; z-weights stay
// register-pinned; gates local; h exchange as round 11.
// Epilogue: wdtile + two-pass MFMA vocab GEMM (exp+rowsum, then write).

#define NB 16
#define NT 64
#define NS 128
#define DE 512
#define NU 256
#define NV 32000

// ws layout (floats); total 18.10 MB (proven available)
static const size_t OFF_KEYS  = 0;          // keysT bf16 [16][256][128] -> 262144
static const size_t OFF_HX    = 262144;     // hx dbuf [2][16][256] -> 8192
static const size_t OFF_PX    = 270336;     // px dbuf [2][16][128] -> 4096
static const size_t OFF_RS    = 294912;     // rowsums [1024]
static const size_t OFF_BAR   = 295936;     // flags[16][64]: [b*64+0..7]=pflag, [+8..15]=hflag
static const size_t OFF_HBUF  = 296960;     // Hb fragment-tiled bf16 -> 131072
static const size_t OFF_W1P   = 428032;     // W1 f16-packed [128][256] uint -> 32768
static const size_t OFF_ENCWX = 460800;     // [16*128][1024] fp32 -> 2097152
static const size_t OFF_ZEMB  = 2557952;    // [16*64][1024] fp32 -> 1048576
static const size_t OFF_WDT   = 428032;     // wdT bf16 tiled (4096000 fl), after recur

typedef __attribute__((ext_vector_type(8))) short bf16x8;
typedef __attribute__((ext_vector_type(4))) float f32x4;
typedef __attribute__((ext_vector_type(2))) _Float16 f16x2;

__device__ __forceinline__ float bf2f(unsigned int us) { return __uint_as_float(us << 16); }
__device__ __forceinline__ unsigned short f2bf(float f) {
    unsigned int u = __float_as_uint(f);
    return (unsigned short)((u + 0x7fffu + ((u >> 16) & 1u)) >> 16);
}
__device__ __forceinline__ float rcp_fast(float x) { return __builtin_amdgcn_rcpf(x); }
__device__ __forceinline__ float sigm(float x) { return rcp_fast(1.0f + __expf(-x)); }
__device__ __forceinline__ float tanh1(float x) {
    float e = __expf(2.0f * x);
    return 1.0f - 2.0f * rcp_fast(e + 1.0f);
}
__device__ __forceinline__ void cstore(float* p, float v) {
    __hip_atomic_store(p, v, __ATOMIC_RELAXED, __HIP_MEMORY_SCOPE_AGENT);
}
__device__ __forceinline__ float cload(const float* p) {
    return __hip_atomic_load(p, __ATOMIC_RELAXED, __HIP_MEMORY_SCOPE_AGENT);
}
__device__ __forceinline__ void cstore_i(int* p, int v) {
    __hip_atomic_store(p, v, __ATOMIC_RELAXED, __HIP_MEMORY_SCOPE_AGENT);
}
__device__ __forceinline__ int cload_i(const int* p) {
    return __hip_atomic_load(p, __ATOMIC_RELAXED, __HIP_MEMORY_SCOPE_AGENT);
}

#if __has_builtin(__builtin_amdgcn_fdot2)
__device__ __forceinline__ float dot2(f16x2 w, f16x2 h, float a) {
    return __builtin_amdgcn_fdot2(w, h, a, false);
}
#else
__device__ __forceinline__ float dot2(f16x2 w, f16x2 h, float a) {
    return fmaf((float)w.x, (float)h.x, fmaf((float)w.y, (float)h.y, a));
}
#endif

// ---------------- fused prologue: init | w1pack(f16) | keys | encwx | zemb ----------------
__launch_bounds__(256)
__global__ void prologue_kernel(const int* __restrict__ dec, const float* __restrict__ enc,
                                const float* __restrict__ emb, const float* __restrict__ W1,
                                const float* __restrict__ W2, const float* __restrict__ b2,
                                const float* __restrict__ Wx, const float* __restrict__ b_lstm,
                                float* __restrict__ rs, int* __restrict__ bar,
                                unsigned int* __restrict__ W1h, unsigned short* __restrict__ keysT,
                                float* __restrict__ encWx, float* __restrict__ zemb) {
    int blk = blockIdx.x, tid = threadIdx.x;
    if (blk < 4) {
        int idx = blk * 256 + tid;
        rs[idx] = 0.f;
        bar[idx] = 0;
    } else if (blk < 132) {
        int id = (blk - 4) * 256 + tid;
        int dp = id >> 8, u = id & 255;
        unsigned short lo = __builtin_bit_cast(unsigned short, (_Float16)W1[(size_t)(2 * dp) * NU + u]);
        unsigned short hi = __builtin_bit_cast(unsigned short, (_Float16)W1[(size_t)(2 * dp + 1) * NU + u]);
        W1h[id] = (unsigned int)lo | ((unsigned int)hi << 16);
    } else if (blk < 260) {
        int bb = (blk - 132) >> 3, sg = (blk - 132) & 7;
        int u = tid;
        float acc[16];
        float bias = b2[u];
#pragma unroll
        for (int r = 0; r < 16; r++) acc[r] = bias;
        const float4* e4 = (const float4*)(enc + ((size_t)bb * NS + sg * 16) * DE);
        const float* wp = W2 + u;
        for (int k4 = 0; k4 < DE / 4; k4++) {
            float w0 = wp[(size_t)(k4 * 4 + 0) * NU];
            float w1 = wp[(size_t)(k4 * 4 + 1) * NU];
            float w2v = wp[(size_t)(k4 * 4 + 2) * NU];
            float w3v = wp[(size_t)(k4 * 4 + 3) * NU];
#pragma unroll
            for (int r = 0; r < 16; r++) {
                float4 e = e4[(size_t)r * (DE / 4) + k4];  // wave-uniform
                acc[r] = fmaf(e.x, w0, fmaf(e.y, w1, fmaf(e.z, w2v, fmaf(e.w, w3v, acc[r]))));
            }
        }
        unsigned int ow[8];
#pragma unroll
        for (int i = 0; i < 8; i++)
            ow[i] = (unsigned int)f2bf(acc[2 * i]) | ((unsigned int)f2bf(acc[2 * i + 1]) << 16);
        uint4* dst = (uint4*)(keysT + ((size_t)bb * NU + u) * NS + sg * 16);
        dst[0] = make_uint4(ow[0], ow[1], ow[2], ow[3]);
        dst[1] = make_uint4(ow[4], ow[5], ow[6], ow[7]);
    } else if (blk < 516) {
        int rg = (blk - 260) >> 2, jq = (blk - 260) & 3;
        int j = jq * 256 + tid;
        float acc[32];
#pragma unroll
        for (int r = 0; r < 32; r++) acc[r] = 0.f;
        const float4* e4 = (const float4*)(enc + (size_t)rg * 32 * DE);
        const float* wp = Wx + j;
        for (int k4 = 0; k4 < DE / 4; k4++) {
            float w0 = wp[(size_t)(k4 * 4 + 0) * 1024];
            float w1 = wp[(size_t)(k4 * 4 + 1) * 1024];
            float w2v = wp[(size_t)(k4 * 4 + 2) * 1024];
            float w3v = wp[(size_t)(k4 * 4 + 3) * 1024];
#pragma unroll
            for (int r = 0; r < 32; r++) {
                float4 e = e4[(size_t)r * (DE / 4) + k4];  // wave-uniform
                acc[r] = fmaf(e.x, w0, fmaf(e.y, w1, fmaf(e.z, w2v, fmaf(e.w, w3v, acc[r]))));
            }
        }
#pragma unroll
        for (int r = 0; r < 32; r++) encWx[(size_t)(rg * 32 + r) * 1024 + j] = acc[r];
    } else {
        int rg = (blk - 516) >> 2, jq = (blk - 516) & 3;
        int j = jq * 256 + tid;
        int tokr[32];
#pragma unroll
        for (int r = 0; r < 32; r++) {
            int row = rg * 32 + r;
            int tok = dec[(row >> 6) * NT + (row & 63)];
            tokr[r] = (tok < 0) ? 0 : (tok >= NV ? NV - 1 : tok);
        }
        float acc[32];
        float bias = b_lstm[j];
#pragma unroll
        for (int r = 0; r < 32; r++) acc[r] = bias;
        const float* wp = Wx + (size_t)512 * 1024 + j;
        for (int k4 = 0; k4 < NU / 4; k4++) {
            float w0 = wp[(size_t)(k4 * 4 + 0) * 1024];
            float w1 = wp[(size_t)(k4 * 4 + 1) * 1024];
            float w2v = wp[(size_t)(k4 * 4 + 2) * 1024];
            float w3v = wp[(size_t)(k4 * 4 + 3) * 1024];
#pragma unroll
            for (int r = 0; r < 32; r++) {
                float4 e = ((const float4*)(emb + (size_t)tokr[r] * NU))[k4];  // uniform
                acc[r] = fmaf(e.x, w0, fmaf(e.y, w1, fmaf(e.z, w2v, fmaf(e.w, w3v, acc[r]))));
            }
        }
#pragma unroll
        for (int r = 0; r < 32; r++) zemb[(size_t)(rg * 32 + r) * 1024 + j] = acc[r];
    }
}

// ---------------- Wd -> fragment-tiled bf16 (after recur) ----------------
__launch_bounds__(256)
__global__ void wdtile_kernel(const float* __restrict__ Wd, unsigned short* __restrict__ wdT) {
    int id = blockIdx.x * 256 + threadIdx.x;
    int l = id & 63, c16 = (id >> 6) & 7, ks = (id >> 9) & 7, p = id >> 12;
    int v = p * 128 + c16 * 16 + (l & 15);
    int k0 = ks * 32 + (l >> 4) * 8;
    unsigned int wout[4];
#pragma unroll
    for (int jj = 0; jj < 4; jj++) {
        unsigned int lo = f2bf(Wd[(size_t)(k0 + 2 * jj) * NV + v]);
        unsigned int hi = f2bf(Wd[(size_t)(k0 + 2 * jj + 1) * NV + v]);
        wout[jj] = lo | (hi << 16);
    }
    *(uint4*)(wdT + (size_t)id * 8) = make_uint4(wout[0], wout[1], wout[2], wout[3]);
}

// ---------------- persistent recurrence: split scores + p/h flag exchanges ----------------
__launch_bounds__(512, 2)
__global__ void recur_kernel(const float* __restrict__ b1, const float* __restrict__ Va,
                             const float* __restrict__ bV, const float* __restrict__ Wh,
                             const float* __restrict__ h0, const float* __restrict__ c0,
                             const unsigned short* __restrict__ keysT,
                             const unsigned int* __restrict__ W1h,
                             const float* __restrict__ encWx, const float* __restrict__ zemb,
                             float* __restrict__ hx, float* __restrict__ px,
                             unsigned short* __restrict__ Hb, int* __restrict__ flags) {
    __shared__ float smem[21504];  // 86 KB pad: 1 block/CU
    float* hl = smem;                        // 256
    _Float16* hf = (_Float16*)(smem + 256);  // 256 f16
    float* qred = smem + 384;                // 512
    float* qv = smem + 896;                  // 256
    float* scp = smem + 1152;                // 512 (score partials)
    float* red = smem + 1664;                // 136
    float* attnp = smem + 1800;              // 128 (raw exp p, gathered)
    float* zred = smem + 1928;               // 512

    int tid = threadIdx.x;
    int b = blockIdx.x & 15;        // gang = batch
    int r = blockIdx.x >> 4;        // 0..7
    int kg = tid >> 7, jl = tid & 127;
    int g = jl >> 5, i32 = jl & 31;
    int j = g * 256 + r * 32 + i32;  // block owns all 4 gates for u in [r*32, r*32+32)
    int* pflag = flags + b * 64;     // [0..7]
    int* hflag = flags + b * 64 + 8; // [8..15]

    float bV0 = bV[0];
    float c_reg = (tid < 32) ? c0[b * NU + r * 32 + tid] : 0.f;

    // pin 96 z-weights/thread: k = kg*96+kk; k<128 -> attn (encWx col j), else h (Wh col j)
    float wreg[96];
    {
        const float* ew = encWx + (size_t)b * 128 * 1024 + j;
        const float* wh = Wh + j;
#pragma unroll
        for (int kk = 0; kk < 96; kk++) {
            int k = kg * 96 + kk;
            wreg[kk] = (k < 128) ? ew[(size_t)k * 1024] : wh[(size_t)(k - 128) * 1024];
        }
    }

    for (int it = 0; it < NT; ++it) {
        // zemb prefetch (gates, tid<32)
        float zpre4[4];
        if (tid < 32) {
#pragma unroll
            for (int gg = 0; gg < 4; gg++)
                zpre4[gg] = zemb[((size_t)b * NT + it) * 1024 + gg * 256 + r * 32 + tid];
        }
        // ---- acquire h_t ----
        if (tid < NU) {
            float hv;
            if (it == 0) {
                hv = h0[b * NU + tid];
            } else {
                int lane = tid & 63;
                while (true) {
                    int f = cload_i(hflag + (lane & 7));
                    if (__all(f >= it)) break;
                    __builtin_amdgcn_s_sleep(2);
                }
                hv = cload(hx + (size_t)(it & 1) * 4096 + b * NU + tid);
            }
            hl[tid] = hv;
            hf[tid] = (_Float16)hv;
        }
        __syncthreads();  // S1

        // ---- q = h @ W1(f16 dot2): replicated; 512 thr = 256 u x 2 d-halves ----
        {
            int u0 = tid & 255, dh = tid >> 8;
            const unsigned int* wp = W1h + dh * 64 * 256 + u0;
            const f16x2* hp = (const f16x2*)hf + dh * 64;
            float a = 0.f;
#pragma unroll 8
            for (int dp = 0; dp < 64; dp++) {
                f16x2 wv = __builtin_bit_cast(f16x2, wp[(size_t)dp * 256]);
                a = dot2(wv, hp[dp], a);
            }
            qred[dh * 256 + u0] = a;
        }
        __syncthreads();  // S2
        if (tid < NU) qv[tid] = qred[tid] + qred[256 + tid] + b1[tid];
        __syncthreads();  // S3

        // ---- scores SLICE: s in [r*16, r*16+16); thread = (sl:16, uc:32 x 8u) ----
        {
            int sl = tid & 15, uc = tid >> 4;
            int s = r * 16 + sl;
            const unsigned short* kp = keysT + ((size_t)b * NU + uc * 8) * NS + s;
            float sc = 0.f;
#pragma unroll
            for (int i = 0; i < 8; i++)
                sc = fmaf(tanh1(qv[uc * 8 + i] + bf2f(kp[(size_t)i * NS])), Va[uc * 8 + i], sc);
            scp[uc * 16 + sl] = sc;
        }
        __syncthreads();  // S4
        // reduce 32 chunks per s; p = exp(score); publish p-slice
        if (tid < 16) {
            float sum = bV0;
#pragma unroll
            for (int k = 0; k < 32; k++) sum += scp[k * 16 + tid];
            float p = __expf(sum);
            cstore(px + (size_t)(it & 1) * 2048 + b * NS + r * 16 + tid, p);
        }
        if (tid < 64) asm volatile("s_waitcnt vmcnt(0)" ::: "memory");
        if (tid == 0) cstore_i(pflag + r, it + 1);
        // ---- gather p (tid<128 poll + load) ----
        if (tid < 128) {
            int lane = tid & 63;
            while (true) {
                int f = cload_i(pflag + (lane & 7));
                if (__all(f >= it + 1)) break;
                __builtin_amdgcn_s_sleep(1);
            }
            float pl = cload(px + (size_t)(it & 1) * 2048 + b * NS + tid);
            attnp[tid] = pl;
            red[tid] = pl;
        }
        __syncthreads();  // S5
        // wave 0: tot reduce (overlaps other waves' z h-part below)
        if (tid < 64) {
            float v = red[tid] + red[tid + 64];
#pragma unroll
            for (int off = 32; off >= 1; off >>= 1) v += __shfl_xor(v, off, 64);
            if (tid == 0) red[128] = v;
        }
        // ---- z slice: 96 register-weight FMAs, attn part unnormalized ----
        float aA = 0.f, aH = 0.f;
        if (kg == 0) {
#pragma unroll
            for (int kk = 0; kk < 96; kk++) aA = fmaf(wreg[kk], attnp[kk], aA);
        } else if (kg == 1) {
#pragma unroll
            for (int kk = 0; kk < 32; kk++) aA = fmaf(wreg[kk], attnp[96 + kk], aA);
#pragma unroll
            for (int kk = 32; kk < 96; kk++) aH = fmaf(wreg[kk], hl[kk - 32], aH);
        } else {
            int base = kg * 96 - 128;
#pragma unroll
            for (int kk = 0; kk < 96; kk++) aH = fmaf(wreg[kk], hl[base + kk], aH);
        }
        __syncthreads();  // S6 (red[128] ready)
        float rinv = rcp_fast(red[128]);
        zred[kg * 128 + jl] = aA * rinv + aH;
        __syncthreads();  // S7

        // ---- local gates (tid<32) ----
        if (tid < 32) {
            float z4[4];
#pragma unroll
            for (int gg = 0; gg < 4; gg++) {
                int jj = gg * 32 + tid;
                z4[gg] = zred[jj] + zred[128 + jj] + zred[256 + jj] + zred[384 + jj] + zpre4[gg];
            }
            float cn = sigm(z4[1]) * c_reg + sigm(z4[0]) * tanh1(z4[2]);
            c_reg = cn;
            float hn = sigm(z4[3]) * tanh1(cn);
            int u = r * 32 + tid;
            int rr = it * NB + b;
            int mp = rr >> 7, lr = rr & 127;
            int chunk = ((u >> 5) * 8 + (lr >> 4)) * 64 + ((u >> 3) & 3) * 16 + (lr & 15);
            Hb[(size_t)mp * 32768 + chunk * 8 + (u & 7)] = f2bf(hn);
            cstore(hx + (size_t)((it + 1) & 1) * 4096 + b * NU + u, hn);
        }
        if (tid < 64) asm volatile("s_waitcnt vmcnt(0)" ::: "memory");
        if (tid == 0) cstore_i(hflag + r, it + 1);
        // next-step polls provide ordering; no trailing block sync needed
    }
}

// ---------------- two-pass vocab GEMM: PASS 0 = exp+rowsum, PASS 1 = write ----------------
template <int PASS>
__launch_bounds__(256)
__global__ void gemm_kernel(const unsigned short* __restrict__ Hb,
                            const unsigned short* __restrict__ wdT,
                            const float* __restrict__ bd, float* __restrict__ out,
                            float* __restrict__ rs) {
    int w = (blockIdx.x & 7) * 250 + (blockIdx.x >> 3);
    int np = w >> 3, mp = w & 7;
    int wave = threadIdx.x >> 6, l = threadIdx.x & 63;
    int wm = wave >> 1, wn = wave & 1;
    const bf16x8* A = (const bf16x8*)Hb + (size_t)mp * 4096;
    const bf16x8* B = (const bf16x8*)wdT + (size_t)np * 4096;
    f32x4 acc[4][4];
#pragma unroll
    for (int mf = 0; mf < 4; mf++)
#pragma unroll
        for (int nf = 0; nf < 4; nf++) acc[mf][nf] = (f32x4){0.f, 0.f, 0.f, 0.f};
#pragma unroll
    for (int ks = 0; ks < 8; ks++) {
        bf16x8 av[4], bv[4];
#pragma unroll
        for (int mf = 0; mf < 4; mf++) av[mf] = A[(ks * 8 + wm * 4 + mf) * 64 + l];
#pragma unroll
        for (int nf = 0; nf < 4; nf++) bv[nf] = B[(ks * 8 + wn * 4 + nf) * 64 + l];
#pragma unroll
        for (int mf = 0; mf < 4; mf++)
#pragma unroll
            for (int nf = 0; nf < 4; nf++)
                acc[mf][nf] =
                    __builtin_amdgcn_mfma_f32_16x16x32_bf16(av[mf], bv[nf], acc[mf][nf], 0, 0, 0);
    }
    int colg = np * 128 + wn * 64;
    int rowg = mp * 128 + wm * 64;
#pragma unroll
    for (int mf = 0; mf < 4; mf++) {
        float rloc[4] = {0.f, 0.f, 0.f, 0.f};
        float rinv[4];
        if constexpr (PASS == 1) {
#pragma unroll
            for (int reg = 0; reg < 4; reg++)
                rinv[reg] = 1.0f / rs[rowg + mf * 16 + (l >> 4) * 4 + reg];
        }
#pragma unroll
        for (int nf = 0; nf < 4; nf++) {
            int col = colg + nf * 16 + (l & 15);
            float bdv = bd[col];
#pragma unroll
            for (int reg = 0; reg < 4; reg++) {
                float p = __expf(acc[mf][nf][reg] + bdv);
                if constexpr (PASS == 0) {
                    rloc[reg] += p;
                } else {
                    int rr = rowg + mf * 16 + (l >> 4) * 4 + reg;  // rr = t*16 + b
                    out[(size_t)((rr & 15) * NT + (rr >> 4)) * NV + col] = p * rinv[reg];
                }
            }
        }
        if constexpr (PASS == 0) {
#pragma unroll
            for (int reg = 0; reg < 4; reg++) {
                float v = rloc[reg];
                v += __shfl_xor(v, 1);
                v += __shfl_xor(v, 2);
                v += __shfl_xor(v, 4);
                v += __shfl_xor(v, 8);
                if ((l & 15) == 0) atomicAdd(&rs[rowg + mf * 16 + (l >> 4) * 4 + reg], v);
            }
        }
    }
}

extern "C" void kernel_launch(void* const* d_in, const int* in_sizes, int n_in,
                              void* d_out, int out_size, void* d_ws, size_t ws_size,
                              hipStream_t stream) {
    const int* dec = (const int*)d_in[0];
    const float* enc = (const float*)d_in[1];
    const float* h0 = (const float*)d_in[2];
    const float* c0 = (const float*)d_in[3];
    const float* emb = (const float*)d_in[4];
    const float* W1 = (const float*)d_in[5];
    const float* b1 = (const float*)d_in[6];
    const float* W2 = (const float*)d_in[7];
    const float* b2 = (const float*)d_in[8];
    const float* Va = (const float*)d_in[9];
    const float* bV = (const float*)d_in[10];
    const float* Wx = (const float*)d_in[11];
    const float* Wh = (const float*)d_in[12];
    const float* b_lstm = (const float*)d_in[13];
    const float* Wd = (const float*)d_in[14];
    const float* bd = (const float*)d_in[15];
    float* out = (float*)d_out;
    float* ws = (float*)d_ws;

    unsigned short* keysT = (unsigned short*)(ws + OFF_KEYS);
    float* hx = ws + OFF_HX;
    float* px = ws + OFF_PX;
    float* ws_rs = ws + OFF_RS;
    int* bar = (int*)(ws + OFF_BAR);
    unsigned short* Hb = (unsigned short*)(ws + OFF_HBUF);
    unsigned int* W1h = (unsigned int*)(ws + OFF_W1P);
    float* encWx = ws + OFF_ENCWX;
    float* zemb = ws + OFF_ZEMB;
    unsigned short* wdT = (unsigned short*)(ws + OFF_WDT);

    prologue_kernel<<<644, 256, 0, stream>>>(dec, enc, emb, W1, W2, b2, Wx, b_lstm,
                                             ws_rs, bar, W1h, keysT, encWx, zemb);
    recur_kernel<<<128, 512, 0, stream>>>(b1, Va, bV, Wh, h0, c0, keysT, W1h, encWx, zemb,
                                          hx, px, Hb, bar);
    wdtile_kernel<<<4000, 256, 0, stream>>>(Wd, wdT);  // overwrites W1h/encWx/zemb
    gemm_kernel<0><<<2000, 256, 0, stream>>>(Hb, wdT, bd, out, ws_rs);
    gemm_kernel<1><<<2000, 256, 0, stream>>>(Hb, wdT, bd, out, ws_rs);
}

// Round 13
// 605.231 us; speedup vs baseline: 4.5512x; 1.0594x over previous
//
#include <hip/hip_runtime.h>

// Decoder, B=16, T=64, S=128, D_ENC=512, U=256, V=32000.
// Round 13: flagless tagged-data exchange. p>0 and h+2>0 strictly, so the
// sign bit carries the step tag ((it>>1)&1 per parity slot): producer stores
// tag?-v:v, consumer lanes poll their OWN word until sign matches, fabs to
// decode. No flags, no producer vmcnt drain -> 1 one-way L3 hop per exchange.
// kg0 polls p while kg1-3 compute z's h-part; per-wave shfl tot-reduce.
// Epilogue: wdtile + two-pass MFMA vocab GEMM (exp+rowsum, then write).

#define NB 16
#define NT 64
#define NS 128
#define DE 512
#define NU 256
#define NV 32000

// ws layout (floats); total 18.10 MB (proven available)
static const size_t OFF_KEYS  = 0;          // keysT bf16 [16][256][128] -> 262144
static const size_t OFF_HX    = 262144;     // hx dbuf [2][16][256] -> 8192 (sign-tagged, +2 bias)
static const size_t OFF_PX    = 270336;     // px dbuf [2][16][128] -> 4096 (sign-tagged)
static const size_t OFF_RS    = 294912;     // rowsums [1024]
static const size_t OFF_HBUF  = 296960;     // Hb fragment-tiled bf16 -> 131072
static const size_t OFF_W1P   = 428032;     // W1 f16-packed [128][256] uint -> 32768
static const size_t OFF_ENCWX = 460800;     // [16*128][1024] fp32 -> 2097152
static const size_t OFF_ZEMB  = 2557952;    // [16*64][1024] fp32 -> 1048576
static const size_t OFF_WDT   = 428032;     // wdT bf16 tiled (4096000 fl), after recur

typedef __attribute__((ext_vector_type(8))) short bf16x8;
typedef __attribute__((ext_vector_type(4))) float f32x4;
typedef __attribute__((ext_vector_type(2))) _Float16 f16x2;

__device__ __forceinline__ float bf2f(unsigned int us) { return __uint_as_float(us << 16); }
__device__ __forceinline__ unsigned short f2bf(float f) {
    unsigned int u = __float_as_uint(f);
    return (unsigned short)((u + 0x7fffu + ((u >> 16) & 1u)) >> 16);
}
__device__ __forceinline__ float rcp_fast(float x) { return __builtin_amdgcn_rcpf(x); }
__device__ __forceinline__ float sigm(float x) { return rcp_fast(1.0f + __expf(-x)); }
__device__ __forceinline__ float tanh1(float x) {
    float e = __expf(2.0f * x);
    return 1.0f - 2.0f * rcp_fast(e + 1.0f);
}
__device__ __forceinline__ void cstore(float* p, float v) {
    __hip_atomic_store(p, v, __ATOMIC_RELAXED, __HIP_MEMORY_SCOPE_AGENT);
}
__device__ __forceinline__ float cload(const float* p) {
    return __hip_atomic_load(p, __ATOMIC_RELAXED, __HIP_MEMORY_SCOPE_AGENT);
}

#if __has_builtin(__builtin_amdgcn_fdot2)
__device__ __forceinline__ float dot2(f16x2 w, f16x2 h, float a) {
    return __builtin_amdgcn_fdot2(w, h, a, false);
}
#else
__device__ __forceinline__ float dot2(f16x2 w, f16x2 h, float a) {
    return fmaf((float)w.x, (float)h.x, fmaf((float)w.y, (float)h.y, a));
}
#endif

// poll a single coherent word until its sign bit equals `tag`, return |value|
__device__ __forceinline__ float poll_tagged(const float* p, unsigned tag) {
    float raw = cload(p);
    while ((__float_as_uint(raw) >> 31) != tag) {
        __builtin_amdgcn_s_sleep(1);
        raw = cload(p);
    }
    return __builtin_fabsf(raw);
}

// ---------------- fused prologue ----------------
__launch_bounds__(256)
__global__ void prologue_kernel(const int* __restrict__ dec, const float* __restrict__ enc,
                                const float* __restrict__ emb, const float* __restrict__ W1,
                                const float* __restrict__ W2, const float* __restrict__ b2,
                                const float* __restrict__ Wx, const float* __restrict__ b_lstm,
                                float* __restrict__ rs, float* __restrict__ hx,
                                float* __restrict__ px,
                                unsigned int* __restrict__ W1h, unsigned short* __restrict__ keysT,
                                float* __restrict__ encWx, float* __restrict__ zemb) {
    int blk = blockIdx.x, tid = threadIdx.x;
    if (blk < 4) {
        rs[blk * 256 + tid] = 0.f;
    } else if (blk < 52) {
        // exchange sentinels: slot-0 readers expect NEG first / POS first per tag math.
        // hx slot0 (+2: positive, blocks t=2's neg-expecting read)
        // hx slot1 (-2: negative, blocks t=1's pos-expecting read)
        // px both slots (-1: negative, blocks t=0/t=1 pos-expecting reads)
        int idx = (blk - 4) * 256 + tid;
        if (idx < 4096) hx[idx] = 2.0f;
        else if (idx < 8192) hx[idx] = -2.0f;
        else px[idx - 8192] = -1.0f;
    } else if (blk < 180) {
        int id = (blk - 52) * 256 + tid;
        int dp = id >> 8, u = id & 255;
        unsigned short lo = __builtin_bit_cast(unsigned short, (_Float16)W1[(size_t)(2 * dp) * NU + u]);
        unsigned short hi = __builtin_bit_cast(unsigned short, (_Float16)W1[(size_t)(2 * dp + 1) * NU + u]);
        W1h[id] = (unsigned int)lo | ((unsigned int)hi << 16);
    } else if (blk < 308) {
        int bb = (blk - 180) >> 3, sg = (blk - 180) & 7;
        int u = tid;
        float acc[16];
        float bias = b2[u];
#pragma unroll
        for (int r = 0; r < 16; r++) acc[r] = bias;
        const float4* e4 = (const float4*)(enc + ((size_t)bb * NS + sg * 16) * DE);
        const float* wp = W2 + u;
        for (int k4 = 0; k4 < DE / 4; k4++) {
            float w0 = wp[(size_t)(k4 * 4 + 0) * NU];
            float w1 = wp[(size_t)(k4 * 4 + 1) * NU];
            float w2v = wp[(size_t)(k4 * 4 + 2) * NU];
            float w3v = wp[(size_t)(k4 * 4 + 3) * NU];
#pragma unroll
            for (int r = 0; r < 16; r++) {
                float4 e = e4[(size_t)r * (DE / 4) + k4];  // wave-uniform
                acc[r] = fmaf(e.x, w0, fmaf(e.y, w1, fmaf(e.z, w2v, fmaf(e.w, w3v, acc[r]))));
            }
        }
        unsigned int ow[8];
#pragma unroll
        for (int i = 0; i < 8; i++)
            ow[i] = (unsigned int)f2bf(acc[2 * i]) | ((unsigned int)f2bf(acc[2 * i + 1]) << 16);
        uint4* dst = (uint4*)(keysT + ((size_t)bb * NU + u) * NS + sg * 16);
        dst[0] = make_uint4(ow[0], ow[1], ow[2], ow[3]);
        dst[1] = make_uint4(ow[4], ow[5], ow[6], ow[7]);
    } else if (blk < 564) {
        int rg = (blk - 308) >> 2, jq = (blk - 308) & 3;
        int j = jq * 256 + tid;
        float acc[32];
#pragma unroll
        for (int r = 0; r < 32; r++) acc[r] = 0.f;
        const float4* e4 = (const float4*)(enc + (size_t)rg * 32 * DE);
        const float* wp = Wx + j;
        for (int k4 = 0; k4 < DE / 4; k4++) {
            float w0 = wp[(size_t)(k4 * 4 + 0) * 1024];
            float w1 = wp[(size_t)(k4 * 4 + 1) * 1024];
            float w2v = wp[(size_t)(k4 * 4 + 2) * 1024];
            float w3v = wp[(size_t)(k4 * 4 + 3) * 1024];
#pragma unroll
            for (int r = 0; r < 32; r++) {
                float4 e = e4[(size_t)r * (DE / 4) + k4];  // wave-uniform
                acc[r] = fmaf(e.x, w0, fmaf(e.y, w1, fmaf(e.z, w2v, fmaf(e.w, w3v, acc[r]))));
            }
        }
#pragma unroll
        for (int r = 0; r < 32; r++) encWx[(size_t)(rg * 32 + r) * 1024 + j] = acc[r];
    } else {
        int rg = (blk - 564) >> 2, jq = (blk - 564) & 3;
        int j = jq * 256 + tid;
        int tokr[32];
#pragma unroll
        for (int r = 0; r < 32; r++) {
            int row = rg * 32 + r;
            int tok = dec[(row >> 6) * NT + (row & 63)];
            tokr[r] = (tok < 0) ? 0 : (tok >= NV ? NV - 1 : tok);
        }
        float acc[32];
        float bias = b_lstm[j];
#pragma unroll
        for (int r = 0; r < 32; r++) acc[r] = bias;
        const float* wp = Wx + (size_t)512 * 1024 + j;
        for (int k4 = 0; k4 < NU / 4; k4++) {
            float w0 = wp[(size_t)(k4 * 4 + 0) * 1024];
            float w1 = wp[(size_t)(k4 * 4 + 1) * 1024];
            float w2v = wp[(size_t)(k4 * 4 + 2) * 1024];
            float w3v = wp[(size_t)(k4 * 4 + 3) * 1024];
#pragma unroll
            for (int r = 0; r < 32; r++) {
                float4 e = ((const float4*)(emb + (size_t)tokr[r] * NU))[k4];  // uniform
                acc[r] = fmaf(e.x, w0, fmaf(e.y, w1, fmaf(e.z, w2v, fmaf(e.w, w3v, acc[r]))));
            }
        }
#pragma unroll
        for (int r = 0; r < 32; r++) zemb[(size_t)(rg * 32 + r) * 1024 + j] = acc[r];
    }
}

// ---------------- Wd -> fragment-tiled bf16 (after recur) ----------------
__launch_bounds__(256)
__global__ void wdtile_kernel(const float* __restrict__ Wd, unsigned short* __restrict__ wdT) {
    int id = blockIdx.x * 256 + threadIdx.x;
    int l = id & 63, c16 = (id >> 6) & 7, ks = (id >> 9) & 7, p = id >> 12;
    int v = p * 128 + c16 * 16 + (l & 15);
    int k0 = ks * 32 + (l >> 4) * 8;
    unsigned int wout[4];
#pragma unroll
    for (int jj = 0; jj < 4; jj++) {
        unsigned int lo = f2bf(Wd[(size_t)(k0 + 2 * jj) * NV + v]);
        unsigned int hi = f2bf(Wd[(size_t)(k0 + 2 * jj + 1) * NV + v]);
        wout[jj] = lo | (hi << 16);
    }
    *(uint4*)(wdT + (size_t)id * 8) = make_uint4(wout[0], wout[1], wout[2], wout[3]);
}

// ---------------- persistent recurrence: tagged-data exchange ----------------
__launch_bounds__(512, 2)
__global__ void recur_kernel(const float* __restrict__ b1, const float* __restrict__ Va,
                             const float* __restrict__ bV, const float* __restrict__ Wh,
                             const float* __restrict__ h0, const float* __restrict__ c0,
                             const unsigned short* __restrict__ keysT,
                             const unsigned int* __restrict__ W1h,
                             const float* __restrict__ encWx, const float* __restrict__ zemb,
                             float* __restrict__ hx, float* __restrict__ px,
                             unsigned short* __restrict__ Hb) {
    __shared__ float smem[21504];  // 86 KB pad: 1 block/CU
    float* hl = smem;                        // 256
    _Float16* hf = (_Float16*)(smem + 256);  // 256 f16
    float* qred = smem + 384;                // 512
    float* qv = smem + 896;                  // 256
    float* scp = smem + 1152;                // 512 (score partials)
    float* attnp = smem + 1664;              // 128 (raw p, gathered)
    float* zred = smem + 1792;               // 512

    int tid = threadIdx.x;
    int b = blockIdx.x & 15;        // gang = batch
    int r = blockIdx.x >> 4;        // 0..7
    int kg = tid >> 7, jl = tid & 127;
    int g = jl >> 5, i32 = jl & 31;
    int j = g * 256 + r * 32 + i32;  // block owns all 4 gates for u in [r*32, r*32+32)

    float bV0 = bV[0];
    float c_reg = (tid < 32) ? c0[b * NU + r * 32 + tid] : 0.f;

    // pin 96 z-weights/thread: k = kg*96+kk; k<128 -> attn (encWx col j), else h (Wh col j)
    float wreg[96];
    {
        const float* ew = encWx + (size_t)b * 128 * 1024 + j;
        const float* wh = Wh + j;
#pragma unroll
        for (int kk = 0; kk < 96; kk++) {
            int k = kg * 96 + kk;
            wreg[kk] = (k < 128) ? ew[(size_t)k * 1024] : wh[(size_t)(k - 128) * 1024];
        }
    }

    for (int it = 0; it < NT; ++it) {
        unsigned tag = (unsigned)((it >> 1) & 1);
        // zemb prefetch (gates, tid<32)
        float zpre4[4];
        if (tid < 32) {
#pragma unroll
            for (int gg = 0; gg < 4; gg++)
                zpre4[gg] = zemb[((size_t)b * NT + it) * 1024 + gg * 256 + r * 32 + tid];
        }
        // ---- acquire h_t: per-lane self-poll on tagged data ----
        if (tid < NU) {
            float hv;
            if (it == 0) {
                hv = h0[b * NU + tid];
            } else {
                hv = poll_tagged(hx + (size_t)(it & 1) * 4096 + b * NU + tid, tag) - 2.0f;
            }
            hl[tid] = hv;
            hf[tid] = (_Float16)hv;
        }
        __syncthreads();  // S1

        // ---- q = h @ W1(f16 dot2): replicated; 512 thr = 256 u x 2 d-halves ----
        {
            int u0 = tid & 255, dh = tid >> 8;
            const unsigned int* wp = W1h + dh * 64 * 256 + u0;
            const f16x2* hp = (const f16x2*)hf + dh * 64;
            float a = 0.f;
#pragma unroll 8
            for (int dp = 0; dp < 64; dp++) {
                f16x2 wv = __builtin_bit_cast(f16x2, wp[(size_t)dp * 256]);
                a = dot2(wv, hp[dp], a);
            }
            qred[dh * 256 + u0] = a;
        }
        __syncthreads();  // S2
        if (tid < NU) qv[tid] = qred[tid] + qred[256 + tid] + b1[tid];
        __syncthreads();  // S3

        // ---- scores SLICE: s in [r*16, r*16+16); thread = (sl:16, uc:32 x 8u) ----
        {
            int sl = tid & 15, uc = tid >> 4;
            int s = r * 16 + sl;
            const unsigned short* kp = keysT + ((size_t)b * NU + uc * 8) * NS + s;
            float sc = 0.f;
#pragma unroll
            for (int i = 0; i < 8; i++)
                sc = fmaf(tanh1(qv[uc * 8 + i] + bf2f(kp[(size_t)i * NS])), Va[uc * 8 + i], sc);
            scp[uc * 16 + sl] = sc;
        }
        __syncthreads();  // S4
        // publish p-slice (tagged; no flag, no drain)
        if (tid < 16) {
            float sum = bV0;
#pragma unroll
            for (int k = 0; k < 32; k++) sum += scp[k * 16 + tid];
            float p = __expf(sum);  // p >= e^-14 > 0 strictly
            cstore(px + (size_t)(it & 1) * 2048 + b * NS + r * 16 + tid, tag ? -p : p);
        }
        // z h-part while the p-exchange is in flight (kg0 has none -> it polls)
        float aH = 0.f;
        if (kg == 1) {
#pragma unroll
            for (int kk = 32; kk < 96; kk++) aH = fmaf(wreg[kk], hl[kk - 32], aH);
        } else if (kg >= 2) {
            int base = kg * 96 - 128;
#pragma unroll
            for (int kk = 0; kk < 96; kk++) aH = fmaf(wreg[kk], hl[base + kk], aH);
        }
        // gather p: kg0 lanes each poll their own word
        if (tid < 128) {
            attnp[tid] = poll_tagged(px + (size_t)(it & 1) * 2048 + b * NS + tid, tag);
        }
        __syncthreads();  // S5
        // per-wave tot reduce (no extra barrier)
        float tot;
        {
            int lane = tid & 63;
            float v = attnp[lane] + attnp[64 + lane];
#pragma unroll
            for (int off = 32; off >= 1; off >>= 1) v += __shfl_xor(v, off, 64);
            tot = v;
        }
        // attn-part FMAs
        float aA = 0.f;
        if (kg == 0) {
#pragma unroll
            for (int kk = 0; kk < 96; kk++) aA = fmaf(wreg[kk], attnp[kk], aA);
        } else if (kg == 1) {
#pragma unroll
            for (int kk = 0; kk < 32; kk++) aA = fmaf(wreg[kk], attnp[96 + kk], aA);
        }
        zred[kg * 128 + jl] = aA * rcp_fast(tot) + aH;
        __syncthreads();  // S6

        // ---- local gates (tid<32) ----
        if (tid < 32) {
            float z4[4];
#pragma unroll
            for (int gg = 0; gg < 4; gg++) {
                int jj = gg * 32 + tid;
                z4[gg] = zred[jj] + zred[128 + jj] + zred[256 + jj] + zred[384 + jj] + zpre4[gg];
            }
            float cn = sigm(z4[1]) * c_reg + sigm(z4[0]) * tanh1(z4[2]);
            c_reg = cn;
            float hn = sigm(z4[3]) * tanh1(cn);
            int u = r * 32 + tid;
            int rr = it * NB + b;
            int mp = rr >> 7, lr = rr & 127;
            int chunk = ((u >> 5) * 8 + (lr >> 4)) * 64 + ((u >> 3) & 3) * 16 + (lr & 15);
            Hb[(size_t)mp * 32768 + chunk * 8 + (u & 7)] = f2bf(hn);
            // publish h for step it+1 (tagged, biased +2; |hn|<=1 so hn+2>=1>0)
            unsigned ntag = (unsigned)(((it + 1) >> 1) & 1);
            float enc = hn + 2.0f;
            cstore(hx + (size_t)((it + 1) & 1) * 4096 + b * NU + u, ntag ? -enc : enc);
        }
        // no trailing sync: next step's polls order everything
    }
}

// ---------------- two-pass vocab GEMM: PASS 0 = exp+rowsum, PASS 1 = write ----------------
template <int PASS>
__launch_bounds__(256)
__global__ void gemm_kernel(const unsigned short* __restrict__ Hb,
                            const unsigned short* __restrict__ wdT,
                            const float* __restrict__ bd, float* __restrict__ out,
                            float* __restrict__ rs) {
    int w = (blockIdx.x & 7) * 250 + (blockIdx.x >> 3);
    int np = w >> 3, mp = w & 7;
    int wave = threadIdx.x >> 6, l = threadIdx.x & 63;
    int wm = wave >> 1, wn = wave & 1;
    const bf16x8* A = (const bf16x8*)Hb + (size_t)mp * 4096;
    const bf16x8* B = (const bf16x8*)wdT + (size_t)np * 4096;
    f32x4 acc[4][4];
#pragma unroll
    for (int mf = 0; mf < 4; mf++)
#pragma unroll
        for (int nf = 0; nf < 4; nf++) acc[mf][nf] = (f32x4){0.f, 0.f, 0.f, 0.f};
#pragma unroll
    for (int ks = 0; ks < 8; ks++) {
        bf16x8 av[4], bv[4];
#pragma unroll
        for (int mf = 0; mf < 4; mf++) av[mf] = A[(ks * 8 + wm * 4 + mf) * 64 + l];
#pragma unroll
        for (int nf = 0; nf < 4; nf++) bv[nf] = B[(ks * 8 + wn * 4 + nf) * 64 + l];
#pragma unroll
        for (int mf = 0; mf < 4; mf++)
#pragma unroll
            for (int nf = 0; nf < 4; nf++)
                acc[mf][nf] =
                    __builtin_amdgcn_mfma_f32_16x16x32_bf16(av[mf], bv[nf], acc[mf][nf], 0, 0, 0);
    }
    int colg = np * 128 + wn * 64;
    int rowg = mp * 128 + wm * 64;
#pragma unroll
    for (int mf = 0; mf < 4; mf++) {
        float rloc[4] = {0.f, 0.f, 0.f, 0.f};
        float rinv[4];
        if constexpr (PASS == 1) {
#pragma unroll
            for (int reg = 0; reg < 4; reg++)
                rinv[reg] = 1.0f / rs[rowg + mf * 16 + (l >> 4) * 4 + reg];
        }
#pragma unroll
        for (int nf = 0; nf < 4; nf++) {
            int col = colg + nf * 16 + (l & 15);
            float bdv = bd[col];
#pragma unroll
            for (int reg = 0; reg < 4; reg++) {
                float p = __expf(acc[mf][nf][reg] + bdv);
                if constexpr (PASS == 0) {
                    rloc[reg] += p;
                } else {
                    int rr = rowg + mf * 16 + (l >> 4) * 4 + reg;  // rr = t*16 + b
                    out[(size_t)((rr & 15) * NT + (rr >> 4)) * NV + col] = p * rinv[reg];
                }
            }
        }
        if constexpr (PASS == 0) {
#pragma unroll
            for (int reg = 0; reg < 4; reg++) {
                float v = rloc[reg];
                v += __shfl_xor(v, 1);
                v += __shfl_xor(v, 2);
                v += __shfl_xor(v, 4);
                v += __shfl_xor(v, 8);
                if ((l & 15) == 0) atomicAdd(&rs[rowg + mf * 16 + (l >> 4) * 4 + reg], v);
            }
        }
    }
}

extern "C" void kernel_launch(void* const* d_in, const int* in_sizes, int n_in,
                              void* d_out, int out_size, void* d_ws, size_t ws_size,
                              hipStream_t stream) {
    const int* dec = (const int*)d_in[0];
    const float* enc = (const float*)d_in[1];
    const float* h0 = (const float*)d_in[2];
    const float* c0 = (const float*)d_in[3];
    const float* emb = (const float*)d_in[4];
    const float* W1 = (const float*)d_in[5];
    const float* b1 = (const float*)d_in[6];
    const float* W2 = (const float*)d_in[7];
    const float* b2 = (const float*)d_in[8];
    const float* Va = (const float*)d_in[9];
    const float* bV = (const float*)d_in[10];
    const float* Wx = (const float*)d_in[11];
    const float* Wh = (const float*)d_in[12];
    const float* b_lstm = (const float*)d_in[13];
    const float* Wd = (const float*)d_in[14];
    const float* bd = (const float*)d_in[15];
    float* out = (float*)d_out;
    float* ws = (float*)d_ws;

    unsigned short* keysT = (unsigned short*)(ws + OFF_KEYS);
    float* hx = ws + OFF_HX;
    float* px = ws + OFF_PX;
    float* ws_rs = ws + OFF_RS;
    unsigned short* Hb = (unsigned short*)(ws + OFF_HBUF);
    unsigned int* W1h = (unsigned int*)(ws + OFF_W1P);
    float* encWx = ws + OFF_ENCWX;
    float* zemb = ws + OFF_ZEMB;
    unsigned short* wdT = (unsigned short*)(ws + OFF_WDT);

    prologue_kernel<<<692, 256, 0, stream>>>(dec, enc, emb, W1, W2, b2, Wx, b_lstm,
                                             ws_rs, hx, px, W1h, keysT, encWx, zemb);
    recur_kernel<<<128, 512, 0, stream>>>(b1, Va, bV, Wh, h0, c0, keysT, W1h, encWx, zemb,
                                          hx, px, Hb);
    wdtile_kernel<<<4000, 256, 0, stream>>>(Wd, wdT);  // overwrites W1h/encWx/zemb
    gemm_kernel<0><<<2000, 256, 0, stream>>>(Hb, wdT, bd, out, ws_rs);
    gemm_kernel<1><<<2000, 256, 0, stream>>>(Hb, wdT, bd, out, ws_rs);
}